// Round 3
// baseline (385.778 us; speedup 1.0000x reference)
//
#include <hip/hip_runtime.h>
#include <hip/hip_bf16.h>
#include <stdint.h>

typedef __bf16 bf16x8 __attribute__((ext_vector_type(8)));
typedef float f32x4 __attribute__((ext_vector_type(4)));
typedef float f32x16 __attribute__((ext_vector_type(16)));
typedef unsigned short ushort8v __attribute__((ext_vector_type(8)));
typedef unsigned short ushort4v __attribute__((ext_vector_type(4)));

#define MFMA16(a, b, c) __builtin_amdgcn_mfma_f32_16x16x32_bf16(a, b, c, 0, 0, 0)
#define MFMA32(a, b, c) __builtin_amdgcn_mfma_f32_32x32x16_bf16(a, b, c, 0, 0, 0)

__device__ __forceinline__ unsigned short f2bf_u(float f) {
    union { float f; uint32_t u; } cv; cv.f = f;
    uint32_t u = cv.u;
    uint32_t r = (u + 0x7FFFu + ((u >> 16) & 1u)) >> 16;
    return (unsigned short)r;
}

__device__ __forceinline__ uint32_t pkbf(float a, float b) {
    union { __hip_bfloat162 h; uint32_t u; } cv;
    cv.h = __float22bfloat162_rn(make_float2(a, b));
    return cv.u;
}

__device__ __forceinline__ float fexp2(float x) { return __builtin_amdgcn_exp2f(x); }

// ---------------------------------------------------------------------------
// Transpose + cast: Wt[n][k] = bf16(W[k][n]),  W is 1024x1024 fp32 row-major
// ---------------------------------------------------------------------------
__global__ __launch_bounds__(256) void wt_cast(const float* __restrict__ W,
                                               unsigned short* __restrict__ Wt) {
    __shared__ float t[32][33];
    const int tx = threadIdx.x & 31, ty = threadIdx.x >> 5;  // 32 x 8
    const int n0 = blockIdx.x * 32, k0 = blockIdx.y * 32;
#pragma unroll
    for (int i = 0; i < 4; i++) {
        int r = i * 8 + ty;
        t[r][tx] = W[(size_t)(k0 + r) * 1024 + n0 + tx];
    }
    __syncthreads();
#pragma unroll
    for (int i = 0; i < 4; i++) {
        int r = i * 8 + ty;
        Wt[(size_t)(n0 + r) * 1024 + k0 + tx] = f2bf_u(t[tx][r]);
    }
}

// ---------------------------------------------------------------------------
// QKV GEMM: out = relu(A[8192x1024] @ W + bias), A fp32, Wt bf16 [N][K].
// VT_LAYOUT==0: out[((b*16+h)*2048+s)*64+d]   (Q,K: [B,H,S,dh])
// VT_LAYOUT==1: out[((b*16+h)*64+d)*2048+s]   (V transposed: [B,H,dh,S])
// ---------------------------------------------------------------------------
template <int VT_LAYOUT>
__global__ __launch_bounds__(256) void qkv_gemm(const float* __restrict__ A,
                                                const unsigned short* __restrict__ Wt,
                                                const float* __restrict__ bias,
                                                unsigned short* __restrict__ out) {
    __shared__ unsigned short aS[128 * 32];
    __shared__ unsigned short wS[128 * 32];
    const int tid = threadIdx.x;
    const int lane = tid & 63, wave = tid >> 6;
    const int rrow = lane & 15, rgrp = lane >> 4;
    const int m0 = blockIdx.y * 128, n0 = blockIdx.x * 128;
    const int wm = wave >> 1, wn = wave & 1;

    f32x4 acc[4][4];
#pragma unroll
    for (int i = 0; i < 4; i++)
#pragma unroll
        for (int j = 0; j < 4; j++) acc[i][j] = (f32x4)0.0f;

    for (int k0 = 0; k0 < 1024; k0 += 32) {
        __syncthreads();
#pragma unroll
        for (int it = 0; it < 2; it++) {
            const int c = tid + it * 256;          // 512 chunks: 128 rows x 4 k-chunks
            const int row = c >> 2, kc = c & 3;
            const int off = (row * 64 + kc * 16) ^ ((row & 7) << 4);
            const float4* ap =
                reinterpret_cast<const float4*>(A + (size_t)(m0 + row) * 1024 + k0 + kc * 8);
            float4 f0 = ap[0], f1 = ap[1];
            ushort8v av;
            av[0] = f2bf_u(f0.x); av[1] = f2bf_u(f0.y); av[2] = f2bf_u(f0.z); av[3] = f2bf_u(f0.w);
            av[4] = f2bf_u(f1.x); av[5] = f2bf_u(f1.y); av[6] = f2bf_u(f1.z); av[7] = f2bf_u(f1.w);
            *reinterpret_cast<ushort8v*>(reinterpret_cast<char*>(aS) + off) = av;
            ushort8v wv = *reinterpret_cast<const ushort8v*>(
                Wt + (size_t)(n0 + row) * 1024 + k0 + kc * 8);
            *reinterpret_cast<ushort8v*>(reinterpret_cast<char*>(wS) + off) = wv;
        }
        __syncthreads();

        bf16x8 af[4], bfr[4];
#pragma unroll
        for (int mi = 0; mi < 4; mi++) {
            const int r = wm * 64 + mi * 16 + rrow;
            const int off = (r * 64 + rgrp * 16) ^ ((r & 7) << 4);
            af[mi] = *reinterpret_cast<const bf16x8*>(reinterpret_cast<const char*>(aS) + off);
        }
#pragma unroll
        for (int ni = 0; ni < 4; ni++) {
            const int r = wn * 64 + ni * 16 + rrow;
            const int off = (r * 64 + rgrp * 16) ^ ((r & 7) << 4);
            bfr[ni] = *reinterpret_cast<const bf16x8*>(reinterpret_cast<const char*>(wS) + off);
        }
#pragma unroll
        for (int mi = 0; mi < 4; mi++)
#pragma unroll
            for (int ni = 0; ni < 4; ni++)
                acc[mi][ni] = MFMA16(af[mi], bfr[ni], acc[mi][ni]);
    }

#pragma unroll
    for (int mi = 0; mi < 4; mi++) {
#pragma unroll
        for (int ni = 0; ni < 4; ni++) {
            const int n = n0 + wn * 64 + ni * 16 + rrow;
            const float bv = bias[n];
            const int h = n >> 6, d = n & 63;
            const int mbase = m0 + wm * 64 + mi * 16 + rgrp * 4;
            const int b = mbase >> 11, s = mbase & 2047;
            if (VT_LAYOUT) {
                ushort4v pv;
#pragma unroll
                for (int jr = 0; jr < 4; jr++)
                    pv[jr] = f2bf_u(fmaxf(acc[mi][ni][jr] + bv, 0.0f));
                *reinterpret_cast<ushort4v*>(out + ((size_t)((b * 16 + h) * 64 + d)) * 2048 + s) = pv;
            } else {
#pragma unroll
                for (int jr = 0; jr < 4; jr++)
                    out[((size_t)((b * 16 + h) * 2048 + (s + jr))) * 64 + d] =
                        f2bf_u(fmaxf(acc[mi][ni][jr] + bv, 0.0f));
            }
        }
    }
}

// ---------------------------------------------------------------------------
// Flash attention, swapped-QK^T 32x32, zero LDS, software-pipelined loads.
// Q,K: [B,H,S,64] bf16.  Vt: [B,H,64,S] bf16.
// One wave per block; wave owns 32 q-rows of one (b,h). Lane owns q=lane&31.
// Pipeline per 64-key tile: issue V[kt] -> S=mfma32(K[kt],Q) -> issue K[kt+1]
// -> base-2 softmax (defer-max THR=8) -> in-reg P pack -> O += mfma32(P,V).
// XCD swizzle: 8 consecutive (b,h) per XCD -> K/V L2-resident (4MB/XCD).
// ---------------------------------------------------------------------------
__global__ __launch_bounds__(64) void flash_attn(const unsigned short* __restrict__ Qg,
                                                 const unsigned short* __restrict__ Kg,
                                                 const unsigned short* __restrict__ Vt,
                                                 const int* __restrict__ mask,
                                                 float* __restrict__ O) {
    const int lane = threadIdx.x;
    const int c = lane & 31, hi = lane >> 5;
    const int bid = blockIdx.x;                    // 4096 blocks
    const int swz = (bid & 7) * 512 + (bid >> 3);  // XCD-contiguous
    const int bh = swz >> 6;
    const int q0 = (swz & 63) * 32;
    const int b = bh >> 4, h = bh & 15;
    const size_t base = (size_t)bh * (2048 * 64);
    const unsigned short* Qb = Qg + base;
    const unsigned short* Kb = Kg + base;
    const unsigned short* Vb = Vt + base;  // [64][2048]

    // Q B-fragments: qf[ds] = Q[q0+c][ds*16 + hi*8 .. +7]
    bf16x8 qf[4];
#pragma unroll
    for (int ds = 0; ds < 4; ds++)
        qf[ds] = *reinterpret_cast<const bf16x8*>(Qb + (size_t)(q0 + c) * 64 + ds * 16 + hi * 8);

    const int mk = mask[b * 2048 + q0 + c];
    const float sc = mk ? 0.1803368801f : 0.0f;  // 0.125 * log2(e); 0 => uniform row

    float m = 0.0f;
    f32x16 lacc = (f32x16)0.0f;
    f32x16 oacc0 = (f32x16)0.0f, oacc1 = (f32x16)0.0f;

    // K prefetch for kt=0
    bf16x8 kf[8];
#pragma unroll
    for (int ds = 0; ds < 4; ds++) {
        kf[ds]     = *reinterpret_cast<const bf16x8*>(Kb + (size_t)c * 64 + ds * 16 + hi * 8);
        kf[4 + ds] = *reinterpret_cast<const bf16x8*>(Kb + (size_t)(32 + c) * 64 + ds * 16 + hi * 8);
    }

    for (int kt = 0; kt < 32; kt++) {
        // ---- issue V loads for this tile (consumed after softmax) ----
        bf16x8 vf[8];
#pragma unroll
        for (int dn = 0; dn < 2; dn++)
#pragma unroll
            for (int ks = 0; ks < 4; ks++)
                vf[dn * 4 + ks] = *reinterpret_cast<const bf16x8*>(
                    Vb + (size_t)(dn * 32 + c) * 2048 + kt * 64 + ks * 16 + hi * 8);

        // ---- S^T = K Q^T (consumes kf prefetched last iteration) ----
        f32x16 sacc0 = (f32x16)0.0f, sacc1 = (f32x16)0.0f;
#pragma unroll
        for (int ds = 0; ds < 4; ds++) {
            sacc0 = MFMA32(kf[ds], qf[ds], sacc0);
            sacc1 = MFMA32(kf[4 + ds], qf[ds], sacc1);
        }

        // ---- prefetch K for kt+1 (hidden under softmax + PV) ----
        const int kt1 = (kt < 31) ? kt + 1 : 31;
#pragma unroll
        for (int ds = 0; ds < 4; ds++) {
            kf[ds] = *reinterpret_cast<const bf16x8*>(
                Kb + (size_t)(kt1 * 64 + c) * 64 + ds * 16 + hi * 8);
            kf[4 + ds] = *reinterpret_cast<const bf16x8*>(
                Kb + (size_t)(kt1 * 64 + 32 + c) * 64 + ds * 16 + hi * 8);
        }

        // ---- raw row max (in-lane tree + one cross-hi shfl) ----
        float t[16];
#pragma unroll
        for (int j = 0; j < 16; j++) t[j] = fmaxf(sacc0[j], sacc1[j]);
#pragma unroll
        for (int s = 8; s >= 1; s >>= 1)
#pragma unroll
            for (int j = 0; j < s; j++) t[j] = fmaxf(t[j], t[j + s]);
        const float rmax = fmaxf(t[0], __shfl_xor(t[0], 32, 64));
        const float pmax2 = rmax * sc;  // base-2 domain

        // ---- defer-max rescale (rare) ----
        if (__any(pmax2 - m > 8.0f)) {
            const float mn = fmaxf(m, pmax2);
            const float alpha = fexp2(m - mn);
            m = mn;
            lacc *= alpha;
#pragma unroll
            for (int reg = 0; reg < 16; reg++) {
                const float ar = __shfl(alpha, (reg & 3) + 8 * (reg >> 2) + 4 * hi, 64);
                oacc0[reg] *= ar;
                oacc1[reg] *= ar;
            }
        }

        // ---- P = 2^(S*sc - m), vector l accumulation ----
        float p[32];
#pragma unroll
        for (int j = 0; j < 16; j++) {
            p[j]      = fexp2(fmaf(sacc0[j], sc, -m));
            p[16 + j] = fexp2(fmaf(sacc1[j], sc, -m));
            lacc[j] += p[j] + p[16 + j];
        }

        // ---- pack P to bf16 A-fragments (in-register) ----
        uint32_t w0[8], w1[8];
#pragma unroll
        for (int i = 0; i < 8; i++) {
            w0[i] = pkbf(p[2 * i], p[2 * i + 1]);
            w1[i] = pkbf(p[16 + 2 * i], p[16 + 2 * i + 1]);
        }
        uint32_t s00 = __shfl_xor(hi ? w0[0] : w0[2], 32, 64);
        uint32_t s01 = __shfl_xor(hi ? w0[1] : w0[3], 32, 64);
        uint32_t s02 = __shfl_xor(hi ? w0[4] : w0[6], 32, 64);
        uint32_t s03 = __shfl_xor(hi ? w0[5] : w0[7], 32, 64);
        uint32_t s10 = __shfl_xor(hi ? w1[0] : w1[2], 32, 64);
        uint32_t s11 = __shfl_xor(hi ? w1[1] : w1[3], 32, 64);
        uint32_t s12 = __shfl_xor(hi ? w1[4] : w1[6], 32, 64);
        uint32_t s13 = __shfl_xor(hi ? w1[5] : w1[7], 32, 64);

        union { uint32_t u[4]; bf16x8 v; } pa[4];
        if (hi == 0) {
            pa[0].u[0] = w0[0]; pa[0].u[1] = w0[1]; pa[0].u[2] = s00; pa[0].u[3] = s01;
            pa[1].u[0] = w0[4]; pa[1].u[1] = w0[5]; pa[1].u[2] = s02; pa[1].u[3] = s03;
            pa[2].u[0] = w1[0]; pa[2].u[1] = w1[1]; pa[2].u[2] = s10; pa[2].u[3] = s11;
            pa[3].u[0] = w1[4]; pa[3].u[1] = w1[5]; pa[3].u[2] = s12; pa[3].u[3] = s13;
        } else {
            pa[0].u[0] = s00; pa[0].u[1] = s01; pa[0].u[2] = w0[2]; pa[0].u[3] = w0[3];
            pa[1].u[0] = s02; pa[1].u[1] = s03; pa[1].u[2] = w0[6]; pa[1].u[3] = w0[7];
            pa[2].u[0] = s10; pa[2].u[1] = s11; pa[2].u[2] = w1[2]; pa[2].u[3] = w1[3];
            pa[3].u[0] = s12; pa[3].u[1] = s13; pa[3].u[2] = w1[6]; pa[3].u[3] = w1[7];
        }

        // ---- O += P V ----
#pragma unroll
        for (int ks = 0; ks < 4; ks++) {
            oacc0 = MFMA32(pa[ks].v, vf[ks], oacc0);
            oacc1 = MFMA32(pa[ks].v, vf[4 + ks], oacc1);
        }
    }

    // ---- final l: horizontal sum of lacc + cross-hi ----
    float ls = 0.0f;
#pragma unroll
    for (int j = 0; j < 16; j++) ls += lacc[j];
    ls += __shfl_xor(ls, 32, 64);
    const float invl = 1.0f / ls;

#pragma unroll
    for (int reg = 0; reg < 16; reg++) {
        const int rr = (reg & 3) + 8 * (reg >> 2) + 4 * hi;
        const float ir = __shfl(invl, rr, 64);
        const size_t rowoff = (size_t)(b * 2048 + q0 + rr) * 1024 + h * 64 + c;
        O[rowoff]      = oacc0[reg] * ir;
        O[rowoff + 32] = oacc1[reg] * ir;
    }
}

// ---------------------------------------------------------------------------
// Residual + LayerNorm: out = LN(O + queries) * gamma + beta, per row of 1024.
// ---------------------------------------------------------------------------
__global__ __launch_bounds__(256) void resid_ln(const float* __restrict__ O,
                                                const float* __restrict__ Qin,
                                                const float* __restrict__ gamma,
                                                const float* __restrict__ beta,
                                                float* __restrict__ out) {
    __shared__ float red[4];
    const int row = blockIdx.x, tid = threadIdx.x;
    const size_t base = (size_t)row * 1024 + tid * 4;
    float4 o4 = *reinterpret_cast<const float4*>(O + base);
    float4 q4 = *reinterpret_cast<const float4*>(Qin + base);
    float x0 = o4.x + q4.x, x1 = o4.y + q4.y, x2 = o4.z + q4.z, x3 = o4.w + q4.w;

    float s = x0 + x1 + x2 + x3;
#pragma unroll
    for (int off = 32; off >= 1; off >>= 1) s += __shfl_xor(s, off, 64);
    const int w = tid >> 6;
    if ((tid & 63) == 0) red[w] = s;
    __syncthreads();
    const float mean = (red[0] + red[1] + red[2] + red[3]) * (1.0f / 1024.0f);
    __syncthreads();

    const float d0 = x0 - mean, d1 = x1 - mean, d2 = x2 - mean, d3 = x3 - mean;
    float vs = d0 * d0 + d1 * d1 + d2 * d2 + d3 * d3;
#pragma unroll
    for (int off = 32; off >= 1; off >>= 1) vs += __shfl_xor(vs, off, 64);
    if ((tid & 63) == 0) red[w] = vs;
    __syncthreads();
    const float var = (red[0] + red[1] + red[2] + red[3]) * (1.0f / 1024.0f);
    const float rstd = rsqrtf(var + 1e-5f);

    float4 g = *reinterpret_cast<const float4*>(gamma + tid * 4);
    float4 be = *reinterpret_cast<const float4*>(beta + tid * 4);
    float4 r;
    r.x = d0 * rstd * g.x + be.x;
    r.y = d1 * rstd * g.y + be.y;
    r.z = d2 * rstd * g.z + be.z;
    r.w = d3 * rstd * g.w + be.w;
    *reinterpret_cast<float4*>(out + base) = r;
}

// ---------------------------------------------------------------------------
extern "C" void kernel_launch(void* const* d_in, const int* in_sizes, int n_in,
                              void* d_out, int out_size, void* d_ws, size_t ws_size,
                              hipStream_t stream) {
    const float* q_in = (const float*)d_in[0];
    const float* k_in = (const float*)d_in[1];
    const float* v_in = (const float*)d_in[2];
    const int* mask = (const int*)d_in[3];
    const float* Wq = (const float*)d_in[4];
    const float* bq = (const float*)d_in[5];
    const float* Wk = (const float*)d_in[6];
    const float* bk = (const float*)d_in[7];
    const float* Wv = (const float*)d_in[8];
    const float* bv = (const float*)d_in[9];
    const float* gamma = (const float*)d_in[10];
    const float* beta = (const float*)d_in[11];
    float* out = (float*)d_out;

    unsigned short* wtq = (unsigned short*)d_ws;         // 1M bf16
    unsigned short* wtk = wtq + 1024 * 1024;
    unsigned short* wtv = wtk + 1024 * 1024;
    unsigned short* Qb = wtv + 1024 * 1024;              // 8M bf16 each
    unsigned short* Kb = Qb + 8192 * 1024;
    unsigned short* Vtb = Kb + 8192 * 1024;
    float* Obuf = (float*)(Vtb + 8192 * 1024);           // 8M fp32

    dim3 tb(256);
    wt_cast<<<dim3(32, 32), tb, 0, stream>>>(Wq, wtq);
    wt_cast<<<dim3(32, 32), tb, 0, stream>>>(Wk, wtk);
    wt_cast<<<dim3(32, 32), tb, 0, stream>>>(Wv, wtv);
    qkv_gemm<0><<<dim3(8, 64), tb, 0, stream>>>(q_in, wtq, bq, Qb);
    qkv_gemm<0><<<dim3(8, 64), tb, 0, stream>>>(k_in, wtk, bk, Kb);
    qkv_gemm<1><<<dim3(8, 64), tb, 0, stream>>>(v_in, wtv, bv, Vtb);
    flash_attn<<<dim3(4096), dim3(64), 0, stream>>>(Qb, Kb, Vtb, mask, Obuf);
    resid_ln<<<dim3(8192), tb, 0, stream>>>(Obuf, q_in, gamma, beta, out);
}

// Round 4
// 382.461 us; speedup vs baseline: 1.0087x; 1.0087x over previous
//
#include <hip/hip_runtime.h>
#include <hip/hip_bf16.h>
#include <stdint.h>

typedef __bf16 bf16x8 __attribute__((ext_vector_type(8)));
typedef float f32x4 __attribute__((ext_vector_type(4)));
typedef float f32x16 __attribute__((ext_vector_type(16)));
typedef unsigned short ushort8v __attribute__((ext_vector_type(8)));
typedef unsigned short ushort4v __attribute__((ext_vector_type(4)));

#define MFMA16(a, b, c) __builtin_amdgcn_mfma_f32_16x16x32_bf16(a, b, c, 0, 0, 0)
#define MFMA32(a, b, c) __builtin_amdgcn_mfma_f32_32x32x16_bf16(a, b, c, 0, 0, 0)

__device__ __forceinline__ unsigned short f2bf_u(float f) {
    union { float f; uint32_t u; } cv; cv.f = f;
    uint32_t u = cv.u;
    uint32_t r = (u + 0x7FFFu + ((u >> 16) & 1u)) >> 16;
    return (unsigned short)r;
}

__device__ __forceinline__ uint32_t pkbf(float a, float b) {
    union { __hip_bfloat162 h; uint32_t u; } cv;
    cv.h = __float22bfloat162_rn(make_float2(a, b));
    return cv.u;
}

__device__ __forceinline__ float fexp2(float x) { return __builtin_amdgcn_exp2f(x); }

// ---------------------------------------------------------------------------
// Transpose + cast: Wt[n][k] = bf16(W[k][n]),  W is 1024x1024 fp32 row-major
// ---------------------------------------------------------------------------
__global__ __launch_bounds__(256) void wt_cast(const float* __restrict__ W,
                                               unsigned short* __restrict__ Wt) {
    __shared__ float t[32][33];
    const int tx = threadIdx.x & 31, ty = threadIdx.x >> 5;  // 32 x 8
    const int n0 = blockIdx.x * 32, k0 = blockIdx.y * 32;
#pragma unroll
    for (int i = 0; i < 4; i++) {
        int r = i * 8 + ty;
        t[r][tx] = W[(size_t)(k0 + r) * 1024 + n0 + tx];
    }
    __syncthreads();
#pragma unroll
    for (int i = 0; i < 4; i++) {
        int r = i * 8 + ty;
        Wt[(size_t)(n0 + r) * 1024 + k0 + tx] = f2bf_u(t[tx][r]);
    }
}

// ---------------------------------------------------------------------------
// QKV GEMM: out = relu(A[8192x1024] @ W + bias), A fp32, Wt bf16 [N][K].
// VT_LAYOUT==0: out[((b*16+h)*2048+s)*64+d]   (Q,K: [B,H,S,dh])
// VT_LAYOUT==1: out[((b*16+h)*64+d)*2048+s]   (V transposed: [B,H,dh,S])
// ---------------------------------------------------------------------------
template <int VT_LAYOUT>
__global__ __launch_bounds__(256) void qkv_gemm(const float* __restrict__ A,
                                                const unsigned short* __restrict__ Wt,
                                                const float* __restrict__ bias,
                                                unsigned short* __restrict__ out) {
    __shared__ unsigned short aS[128 * 32];
    __shared__ unsigned short wS[128 * 32];
    const int tid = threadIdx.x;
    const int lane = tid & 63, wave = tid >> 6;
    const int rrow = lane & 15, rgrp = lane >> 4;
    const int m0 = blockIdx.y * 128, n0 = blockIdx.x * 128;
    const int wm = wave >> 1, wn = wave & 1;

    f32x4 acc[4][4];
#pragma unroll
    for (int i = 0; i < 4; i++)
#pragma unroll
        for (int j = 0; j < 4; j++) acc[i][j] = (f32x4)0.0f;

    for (int k0 = 0; k0 < 1024; k0 += 32) {
        __syncthreads();
#pragma unroll
        for (int it = 0; it < 2; it++) {
            const int c = tid + it * 256;          // 512 chunks: 128 rows x 4 k-chunks
            const int row = c >> 2, kc = c & 3;
            const int off = (row * 64 + kc * 16) ^ ((row & 7) << 4);
            const float4* ap =
                reinterpret_cast<const float4*>(A + (size_t)(m0 + row) * 1024 + k0 + kc * 8);
            float4 f0 = ap[0], f1 = ap[1];
            ushort8v av;
            av[0] = f2bf_u(f0.x); av[1] = f2bf_u(f0.y); av[2] = f2bf_u(f0.z); av[3] = f2bf_u(f0.w);
            av[4] = f2bf_u(f1.x); av[5] = f2bf_u(f1.y); av[6] = f2bf_u(f1.z); av[7] = f2bf_u(f1.w);
            *reinterpret_cast<ushort8v*>(reinterpret_cast<char*>(aS) + off) = av;
            ushort8v wv = *reinterpret_cast<const ushort8v*>(
                Wt + (size_t)(n0 + row) * 1024 + k0 + kc * 8);
            *reinterpret_cast<ushort8v*>(reinterpret_cast<char*>(wS) + off) = wv;
        }
        __syncthreads();

        bf16x8 af[4], bfr[4];
#pragma unroll
        for (int mi = 0; mi < 4; mi++) {
            const int r = wm * 64 + mi * 16 + rrow;
            const int off = (r * 64 + rgrp * 16) ^ ((r & 7) << 4);
            af[mi] = *reinterpret_cast<const bf16x8*>(reinterpret_cast<const char*>(aS) + off);
        }
#pragma unroll
        for (int ni = 0; ni < 4; ni++) {
            const int r = wn * 64 + ni * 16 + rrow;
            const int off = (r * 64 + rgrp * 16) ^ ((r & 7) << 4);
            bfr[ni] = *reinterpret_cast<const bf16x8*>(reinterpret_cast<const char*>(wS) + off);
        }
#pragma unroll
        for (int mi = 0; mi < 4; mi++)
#pragma unroll
            for (int ni = 0; ni < 4; ni++)
                acc[mi][ni] = MFMA16(af[mi], bfr[ni], acc[mi][ni]);
    }

#pragma unroll
    for (int mi = 0; mi < 4; mi++) {
#pragma unroll
        for (int ni = 0; ni < 4; ni++) {
            const int n = n0 + wn * 64 + ni * 16 + rrow;
            const float bv = bias[n];
            const int h = n >> 6, d = n & 63;
            const int mbase = m0 + wm * 64 + mi * 16 + rgrp * 4;
            const int b = mbase >> 11, s = mbase & 2047;
            if (VT_LAYOUT) {
                ushort4v pv;
#pragma unroll
                for (int jr = 0; jr < 4; jr++)
                    pv[jr] = f2bf_u(fmaxf(acc[mi][ni][jr] + bv, 0.0f));
                *reinterpret_cast<ushort4v*>(out + ((size_t)((b * 16 + h) * 64 + d)) * 2048 + s) = pv;
            } else {
#pragma unroll
                for (int jr = 0; jr < 4; jr++)
                    out[((size_t)((b * 16 + h) * 2048 + (s + jr))) * 64 + d] =
                        f2bf_u(fmaxf(acc[mi][ni][jr] + bv, 0.0f));
            }
        }
    }
}

// ---------------------------------------------------------------------------
// Flash attention, swapped-QK^T 32x32, zero LDS, software-pipelined loads.
// 4 waves/block, each wave = 32 q-rows of one (b,h); __launch_bounds__(256,2)
// pins a 256-VGPR budget (2 waves/SIMD) so nothing spills. Block-level XCD
// swizzle keeps each block's K/V in one XCD's L2.
// Per 64-key tile: issue V[kt] -> S=mfma32(K[kt],Q) -> prefetch K[kt+1]
// -> base-2 softmax in place (defer-max THR=8) -> in-reg P pack -> PV.
// ---------------------------------------------------------------------------
__global__ __launch_bounds__(256, 2) void flash_attn(const unsigned short* __restrict__ Qg,
                                                     const unsigned short* __restrict__ Kg,
                                                     const unsigned short* __restrict__ Vt,
                                                     const int* __restrict__ mask,
                                                     float* __restrict__ O) {
    const int lane = threadIdx.x & 63, wave = threadIdx.x >> 6;
    const int c = lane & 31, hi = lane >> 5;
    const int bid = blockIdx.x;                      // 1024 blocks
    const int swzb = (bid & 7) * 128 + (bid >> 3);   // XCD-contiguous block id
    const int gid = swzb * 4 + wave;                 // global wave id in [0,4096)
    const int bh = gid >> 6;
    const int q0 = (gid & 63) * 32;
    const int b = bh >> 4, h = bh & 15;
    const size_t base = (size_t)bh * (2048 * 64);
    const unsigned short* Qb = Qg + base;
    const unsigned short* Kb = Kg + base;
    const unsigned short* Vb = Vt + base;  // [64][2048]

    // Q B-fragments: qf[ds] = Q[q0+c][ds*16 + hi*8 .. +7]
    bf16x8 qf[4];
#pragma unroll
    for (int ds = 0; ds < 4; ds++)
        qf[ds] = *reinterpret_cast<const bf16x8*>(Qb + (size_t)(q0 + c) * 64 + ds * 16 + hi * 8);

    const int mk = mask[b * 2048 + q0 + c];
    const float sc = mk ? 0.1803368801f : 0.0f;  // 0.125 * log2(e); 0 => uniform row

    float m = 0.0f;
    f32x4 lacc = (f32x4)0.0f;
    f32x16 oacc0 = (f32x16)0.0f, oacc1 = (f32x16)0.0f;

    // K prefetch for kt=0
    bf16x8 kf[8];
#pragma unroll
    for (int ds = 0; ds < 4; ds++) {
        kf[ds]     = *reinterpret_cast<const bf16x8*>(Kb + (size_t)c * 64 + ds * 16 + hi * 8);
        kf[4 + ds] = *reinterpret_cast<const bf16x8*>(Kb + (size_t)(32 + c) * 64 + ds * 16 + hi * 8);
    }

    for (int kt = 0; kt < 32; kt++) {
        // ---- issue V loads for this tile (consumed after softmax) ----
        bf16x8 vf[8];
#pragma unroll
        for (int dn = 0; dn < 2; dn++)
#pragma unroll
            for (int ks = 0; ks < 4; ks++)
                vf[dn * 4 + ks] = *reinterpret_cast<const bf16x8*>(
                    Vb + (size_t)(dn * 32 + c) * 2048 + kt * 64 + ks * 16 + hi * 8);

        // ---- S^T = K Q^T (consumes kf prefetched last iteration) ----
        f32x16 sacc0 = (f32x16)0.0f, sacc1 = (f32x16)0.0f;
        __builtin_amdgcn_s_setprio(1);
#pragma unroll
        for (int ds = 0; ds < 4; ds++) {
            sacc0 = MFMA32(kf[ds], qf[ds], sacc0);
            sacc1 = MFMA32(kf[4 + ds], qf[ds], sacc1);
        }
        __builtin_amdgcn_s_setprio(0);

        // ---- prefetch K for kt+1 (hidden under softmax + PV) ----
        const int kt1 = (kt < 31) ? kt + 1 : 31;
#pragma unroll
        for (int ds = 0; ds < 4; ds++) {
            kf[ds] = *reinterpret_cast<const bf16x8*>(
                Kb + (size_t)(kt1 * 64 + c) * 64 + ds * 16 + hi * 8);
            kf[4 + ds] = *reinterpret_cast<const bf16x8*>(
                Kb + (size_t)(kt1 * 64 + 32 + c) * 64 + ds * 16 + hi * 8);
        }

        // ---- raw row max (in-lane tree + one cross-hi shfl) ----
        float t[16];
#pragma unroll
        for (int j = 0; j < 16; j++) t[j] = fmaxf(sacc0[j], sacc1[j]);
#pragma unroll
        for (int s = 8; s >= 1; s >>= 1)
#pragma unroll
            for (int j = 0; j < s; j++) t[j] = fmaxf(t[j], t[j + s]);
        const float rmax = fmaxf(t[0], __shfl_xor(t[0], 32, 64));
        const float pmax2 = rmax * sc;  // base-2 domain

        // ---- defer-max rescale (rare) ----
        if (__any(pmax2 - m > 8.0f)) {
            const float mn = fmaxf(m, pmax2);
            const float alpha = fexp2(m - mn);
            m = mn;
            lacc *= alpha;
#pragma unroll
            for (int reg = 0; reg < 16; reg++) {
                const float ar = __shfl(alpha, (reg & 3) + 8 * (reg >> 2) + 4 * hi, 64);
                oacc0[reg] *= ar;
                oacc1[reg] *= ar;
            }
        }

        // ---- P = 2^(S*sc - m) in place, vector l accumulation ----
#pragma unroll
        for (int j = 0; j < 16; j++) {
            const float p0 = fexp2(fmaf(sacc0[j], sc, -m));
            const float p1 = fexp2(fmaf(sacc1[j], sc, -m));
            sacc0[j] = p0;
            sacc1[j] = p1;
            lacc[j & 3] += p0 + p1;
        }

        // ---- pack P to bf16 A-fragments (in-register) ----
        uint32_t w0[8], w1[8];
#pragma unroll
        for (int i = 0; i < 8; i++) {
            w0[i] = pkbf(sacc0[2 * i], sacc0[2 * i + 1]);
            w1[i] = pkbf(sacc1[2 * i], sacc1[2 * i + 1]);
        }
        uint32_t s00 = __shfl_xor(hi ? w0[0] : w0[2], 32, 64);
        uint32_t s01 = __shfl_xor(hi ? w0[1] : w0[3], 32, 64);
        uint32_t s02 = __shfl_xor(hi ? w0[4] : w0[6], 32, 64);
        uint32_t s03 = __shfl_xor(hi ? w0[5] : w0[7], 32, 64);
        uint32_t s10 = __shfl_xor(hi ? w1[0] : w1[2], 32, 64);
        uint32_t s11 = __shfl_xor(hi ? w1[1] : w1[3], 32, 64);
        uint32_t s12 = __shfl_xor(hi ? w1[4] : w1[6], 32, 64);
        uint32_t s13 = __shfl_xor(hi ? w1[5] : w1[7], 32, 64);

        union { uint32_t u[4]; bf16x8 v; } pa[4];
        if (hi == 0) {
            pa[0].u[0] = w0[0]; pa[0].u[1] = w0[1]; pa[0].u[2] = s00; pa[0].u[3] = s01;
            pa[1].u[0] = w0[4]; pa[1].u[1] = w0[5]; pa[1].u[2] = s02; pa[1].u[3] = s03;
            pa[2].u[0] = w1[0]; pa[2].u[1] = w1[1]; pa[2].u[2] = s10; pa[2].u[3] = s11;
            pa[3].u[0] = w1[4]; pa[3].u[1] = w1[5]; pa[3].u[2] = s12; pa[3].u[3] = s13;
        } else {
            pa[0].u[0] = s00; pa[0].u[1] = s01; pa[0].u[2] = w0[2]; pa[0].u[3] = w0[3];
            pa[1].u[0] = s02; pa[1].u[1] = s03; pa[1].u[2] = w0[6]; pa[1].u[3] = w0[7];
            pa[2].u[0] = s10; pa[2].u[1] = s11; pa[2].u[2] = w1[2]; pa[2].u[3] = w1[3];
            pa[3].u[0] = s12; pa[3].u[1] = s13; pa[3].u[2] = w1[6]; pa[3].u[3] = w1[7];
        }

        // ---- O += P V ----
        __builtin_amdgcn_s_setprio(1);
#pragma unroll
        for (int ks = 0; ks < 4; ks++) {
            oacc0 = MFMA32(pa[ks].v, vf[ks], oacc0);
            oacc1 = MFMA32(pa[ks].v, vf[4 + ks], oacc1);
        }
        __builtin_amdgcn_s_setprio(0);
    }

    // ---- final l: horizontal sum of lacc + cross-hi ----
    float ls = lacc[0] + lacc[1] + lacc[2] + lacc[3];
    ls += __shfl_xor(ls, 32, 64);
    const float invl = 1.0f / ls;

#pragma unroll
    for (int reg = 0; reg < 16; reg++) {
        const int rr = (reg & 3) + 8 * (reg >> 2) + 4 * hi;
        const float ir = __shfl(invl, rr, 64);
        const size_t rowoff = (size_t)(b * 2048 + q0 + rr) * 1024 + h * 64 + c;
        O[rowoff]      = oacc0[reg] * ir;
        O[rowoff + 32] = oacc1[reg] * ir;
    }
}

// ---------------------------------------------------------------------------
// Residual + LayerNorm: out = LN(O + queries) * gamma + beta, per row of 1024.
// ---------------------------------------------------------------------------
__global__ __launch_bounds__(256) void resid_ln(const float* __restrict__ O,
                                                const float* __restrict__ Qin,
                                                const float* __restrict__ gamma,
                                                const float* __restrict__ beta,
                                                float* __restrict__ out) {
    __shared__ float red[4];
    const int row = blockIdx.x, tid = threadIdx.x;
    const size_t base = (size_t)row * 1024 + tid * 4;
    float4 o4 = *reinterpret_cast<const float4*>(O + base);
    float4 q4 = *reinterpret_cast<const float4*>(Qin + base);
    float x0 = o4.x + q4.x, x1 = o4.y + q4.y, x2 = o4.z + q4.z, x3 = o4.w + q4.w;

    float s = x0 + x1 + x2 + x3;
#pragma unroll
    for (int off = 32; off >= 1; off >>= 1) s += __shfl_xor(s, off, 64);
    const int w = tid >> 6;
    if ((tid & 63) == 0) red[w] = s;
    __syncthreads();
    const float mean = (red[0] + red[1] + red[2] + red[3]) * (1.0f / 1024.0f);
    __syncthreads();

    const float d0 = x0 - mean, d1 = x1 - mean, d2 = x2 - mean, d3 = x3 - mean;
    float vs = d0 * d0 + d1 * d1 + d2 * d2 + d3 * d3;
#pragma unroll
    for (int off = 32; off >= 1; off >>= 1) vs += __shfl_xor(vs, off, 64);
    if ((tid & 63) == 0) red[w] = vs;
    __syncthreads();
    const float var = (red[0] + red[1] + red[2] + red[3]) * (1.0f / 1024.0f);
    const float rstd = rsqrtf(var + 1e-5f);

    float4 g = *reinterpret_cast<const float4*>(gamma + tid * 4);
    float4 be = *reinterpret_cast<const float4*>(beta + tid * 4);
    float4 r;
    r.x = d0 * rstd * g.x + be.x;
    r.y = d1 * rstd * g.y + be.y;
    r.z = d2 * rstd * g.z + be.z;
    r.w = d3 * rstd * g.w + be.w;
    *reinterpret_cast<float4*>(out + base) = r;
}

// ---------------------------------------------------------------------------
extern "C" void kernel_launch(void* const* d_in, const int* in_sizes, int n_in,
                              void* d_out, int out_size, void* d_ws, size_t ws_size,
                              hipStream_t stream) {
    const float* q_in = (const float*)d_in[0];
    const float* k_in = (const float*)d_in[1];
    const float* v_in = (const float*)d_in[2];
    const int* mask = (const int*)d_in[3];
    const float* Wq = (const float*)d_in[4];
    const float* bq = (const float*)d_in[5];
    const float* Wk = (const float*)d_in[6];
    const float* bk = (const float*)d_in[7];
    const float* Wv = (const float*)d_in[8];
    const float* bv = (const float*)d_in[9];
    const float* gamma = (const float*)d_in[10];
    const float* beta = (const float*)d_in[11];
    float* out = (float*)d_out;

    unsigned short* wtq = (unsigned short*)d_ws;         // 1M bf16
    unsigned short* wtk = wtq + 1024 * 1024;
    unsigned short* wtv = wtk + 1024 * 1024;
    unsigned short* Qb = wtv + 1024 * 1024;              // 8M bf16 each
    unsigned short* Kb = Qb + 8192 * 1024;
    unsigned short* Vtb = Kb + 8192 * 1024;
    float* Obuf = (float*)(Vtb + 8192 * 1024);           // 8M fp32

    dim3 tb(256);
    wt_cast<<<dim3(32, 32), tb, 0, stream>>>(Wq, wtq);
    wt_cast<<<dim3(32, 32), tb, 0, stream>>>(Wk, wtk);
    wt_cast<<<dim3(32, 32), tb, 0, stream>>>(Wv, wtv);
    qkv_gemm<0><<<dim3(8, 64), tb, 0, stream>>>(q_in, wtq, bq, Qb);
    qkv_gemm<0><<<dim3(8, 64), tb, 0, stream>>>(k_in, wtk, bk, Kb);
    qkv_gemm<1><<<dim3(8, 64), tb, 0, stream>>>(v_in, wtv, bv, Vtb);
    flash_attn<<<dim3(1024), tb, 0, stream>>>(Qb, Kb, Vtb, mask, Obuf);
    resid_ln<<<dim3(8192), tb, 0, stream>>>(Obuf, q_in, gamma, beta, out);
}

// Round 5
// 262.697 us; speedup vs baseline: 1.4685x; 1.4559x over previous
//
#include <hip/hip_runtime.h>
#include <hip/hip_bf16.h>
#include <stdint.h>

typedef __bf16 bf16x8 __attribute__((ext_vector_type(8)));
typedef float f32x4 __attribute__((ext_vector_type(4)));
typedef float f32x16 __attribute__((ext_vector_type(16)));
typedef unsigned short ushort8v __attribute__((ext_vector_type(8)));
typedef unsigned short ushort4v __attribute__((ext_vector_type(4)));

#define MFMA16(a, b, c) __builtin_amdgcn_mfma_f32_16x16x32_bf16(a, b, c, 0, 0, 0)
#define MFMA32(a, b, c) __builtin_amdgcn_mfma_f32_32x32x16_bf16(a, b, c, 0, 0, 0)

// async global->LDS, 16B per lane; LDS dest = wave-uniform base + lane*16
#define GLOAD_LDS16(g, l)                                                        \
    __builtin_amdgcn_global_load_lds(                                            \
        (const __attribute__((address_space(1))) uint32_t*)(g),                  \
        (__attribute__((address_space(3))) uint32_t*)(l), 16, 0, 0)

__device__ __forceinline__ unsigned short f2bf_u(float f) {
    union { float f; uint32_t u; } cv; cv.f = f;
    uint32_t u = cv.u;
    uint32_t r = (u + 0x7FFFu + ((u >> 16) & 1u)) >> 16;
    return (unsigned short)r;
}

__device__ __forceinline__ uint32_t pkbf(float a, float b) {
    union { __hip_bfloat162 h; uint32_t u; } cv;
    cv.h = __float22bfloat162_rn(make_float2(a, b));
    return cv.u;
}

__device__ __forceinline__ float fexp2(float x) { return __builtin_amdgcn_exp2f(x); }

// ---------------------------------------------------------------------------
// Transpose + cast: Wt[n][k] = bf16(W[k][n]),  W is 1024x1024 fp32 row-major
// ---------------------------------------------------------------------------
__global__ __launch_bounds__(256) void wt_cast(const float* __restrict__ W,
                                               unsigned short* __restrict__ Wt) {
    __shared__ float t[32][33];
    const int tx = threadIdx.x & 31, ty = threadIdx.x >> 5;  // 32 x 8
    const int n0 = blockIdx.x * 32, k0 = blockIdx.y * 32;
#pragma unroll
    for (int i = 0; i < 4; i++) {
        int r = i * 8 + ty;
        t[r][tx] = W[(size_t)(k0 + r) * 1024 + n0 + tx];
    }
    __syncthreads();
#pragma unroll
    for (int i = 0; i < 4; i++) {
        int r = i * 8 + ty;
        Wt[(size_t)(n0 + r) * 1024 + k0 + tx] = f2bf_u(t[tx][r]);
    }
}

// ---------------------------------------------------------------------------
// QKV GEMM: out = relu(A[8192x1024] @ W + bias), A fp32, Wt bf16 [N][K].
// VT_LAYOUT==0: out[((b*16+h)*2048+s)*64+d]   (Q,K: [B,H,S,dh])
// VT_LAYOUT==1: out[((b*16+h)*64+d)*2048+s]   (V transposed: [B,H,dh,S])
// ---------------------------------------------------------------------------
template <int VT_LAYOUT>
__global__ __launch_bounds__(256) void qkv_gemm(const float* __restrict__ A,
                                                const unsigned short* __restrict__ Wt,
                                                const float* __restrict__ bias,
                                                unsigned short* __restrict__ out) {
    __shared__ unsigned short aS[128 * 32];
    __shared__ unsigned short wS[128 * 32];
    const int tid = threadIdx.x;
    const int lane = tid & 63, wave = tid >> 6;
    const int rrow = lane & 15, rgrp = lane >> 4;
    const int m0 = blockIdx.y * 128, n0 = blockIdx.x * 128;
    const int wm = wave >> 1, wn = wave & 1;

    f32x4 acc[4][4];
#pragma unroll
    for (int i = 0; i < 4; i++)
#pragma unroll
        for (int j = 0; j < 4; j++) acc[i][j] = (f32x4)0.0f;

    for (int k0 = 0; k0 < 1024; k0 += 32) {
        __syncthreads();
#pragma unroll
        for (int it = 0; it < 2; it++) {
            const int c = tid + it * 256;          // 512 chunks: 128 rows x 4 k-chunks
            const int row = c >> 2, kc = c & 3;
            const int off = (row * 64 + kc * 16) ^ ((row & 7) << 4);
            const float4* ap =
                reinterpret_cast<const float4*>(A + (size_t)(m0 + row) * 1024 + k0 + kc * 8);
            float4 f0 = ap[0], f1 = ap[1];
            ushort8v av;
            av[0] = f2bf_u(f0.x); av[1] = f2bf_u(f0.y); av[2] = f2bf_u(f0.z); av[3] = f2bf_u(f0.w);
            av[4] = f2bf_u(f1.x); av[5] = f2bf_u(f1.y); av[6] = f2bf_u(f1.z); av[7] = f2bf_u(f1.w);
            *reinterpret_cast<ushort8v*>(reinterpret_cast<char*>(aS) + off) = av;
            ushort8v wv = *reinterpret_cast<const ushort8v*>(
                Wt + (size_t)(n0 + row) * 1024 + k0 + kc * 8);
            *reinterpret_cast<ushort8v*>(reinterpret_cast<char*>(wS) + off) = wv;
        }
        __syncthreads();

        bf16x8 af[4], bfr[4];
#pragma unroll
        for (int mi = 0; mi < 4; mi++) {
            const int r = wm * 64 + mi * 16 + rrow;
            const int off = (r * 64 + rgrp * 16) ^ ((r & 7) << 4);
            af[mi] = *reinterpret_cast<const bf16x8*>(reinterpret_cast<const char*>(aS) + off);
        }
#pragma unroll
        for (int ni = 0; ni < 4; ni++) {
            const int r = wn * 64 + ni * 16 + rrow;
            const int off = (r * 64 + rgrp * 16) ^ ((r & 7) << 4);
            bfr[ni] = *reinterpret_cast<const bf16x8*>(reinterpret_cast<const char*>(wS) + off);
        }
#pragma unroll
        for (int mi = 0; mi < 4; mi++)
#pragma unroll
            for (int ni = 0; ni < 4; ni++)
                acc[mi][ni] = MFMA16(af[mi], bfr[ni], acc[mi][ni]);
    }

#pragma unroll
    for (int mi = 0; mi < 4; mi++) {
#pragma unroll
        for (int ni = 0; ni < 4; ni++) {
            const int n = n0 + wn * 64 + ni * 16 + rrow;
            const float bv = bias[n];
            const int h = n >> 6, d = n & 63;
            const int mbase = m0 + wm * 64 + mi * 16 + rgrp * 4;
            const int b = mbase >> 11, s = mbase & 2047;
            if (VT_LAYOUT) {
                ushort4v pv;
#pragma unroll
                for (int jr = 0; jr < 4; jr++)
                    pv[jr] = f2bf_u(fmaxf(acc[mi][ni][jr] + bv, 0.0f));
                *reinterpret_cast<ushort4v*>(out + ((size_t)((b * 16 + h) * 64 + d)) * 2048 + s) = pv;
            } else {
#pragma unroll
                for (int jr = 0; jr < 4; jr++)
                    out[((size_t)((b * 16 + h) * 2048 + (s + jr))) * 64 + d] =
                        f2bf_u(fmaxf(acc[mi][ni][jr] + bv, 0.0f));
            }
        }
    }
}

// ---------------------------------------------------------------------------
// Flash attention. 4 waves/block share one (b,h); K/V 64-key tiles staged to
// LDS via global_load_lds (double-buffered, 2-phase), XOR-swizzled source so
// swizzled b128 reads are bank-minimal. Swapped-QK^T 32x32, in-reg softmax
// (base-2, defer-max THR=8), per-half P pack to cap VGPR pressure.
// ---------------------------------------------------------------------------
__global__ __launch_bounds__(256, 4) void flash_attn(const unsigned short* __restrict__ Qg,
                                                     const unsigned short* __restrict__ Kg,
                                                     const unsigned short* __restrict__ Vt,
                                                     const int* __restrict__ mask,
                                                     float* __restrict__ O) {
    __shared__ unsigned short ldsK[2][64 * 64];  // 8KB per buffer
    __shared__ unsigned short ldsV[2][64 * 64];
    const int tid = threadIdx.x;
    const int lane = tid & 63, wave = tid >> 6;
    const int c = lane & 31, hi = lane >> 5;
    const int bid = blockIdx.x;                      // 1024 blocks
    const int swzb = (bid & 7) * 128 + (bid >> 3);   // XCD-contiguous block id
    const int gid = swzb * 4 + wave;                 // wave id in [0,4096)
    const int bh = gid >> 6;                         // all 4 waves: same bh
    const int q0 = (gid & 63) * 32;
    const int b = bh >> 4, h = bh & 15;
    const size_t base = (size_t)bh * (2048 * 64);
    const unsigned short* Qb = Qg + base;
    const unsigned short* Kb = Kg + base;
    const unsigned short* Vb = Vt + base;  // [64][2048]

    // staging constants: lane covers 16B chunk (lane&7) of row stripe (lane>>3)
    const int srow = lane >> 3;                 // 0..7
    const int schunk = (lane & 7) ^ srow;       // inverse-swizzled source chunk
    // fragment read offsets (bytes within one 8KB buffer), same XOR
    int offL[4], offH[4];
#pragma unroll
    for (int ds = 0; ds < 4; ds++) {
        offL[ds] = c * 128 + ((((ds << 1) + hi) ^ (c & 7)) << 4);
        offH[ds] = offL[ds] + 32 * 128;
    }

    // Q B-fragments: qf[ds] = Q[q0+c][ds*16 + hi*8 .. +7]
    bf16x8 qf[4];
#pragma unroll
    for (int ds = 0; ds < 4; ds++)
        qf[ds] = *reinterpret_cast<const bf16x8*>(Qb + (size_t)(q0 + c) * 64 + ds * 16 + hi * 8);

    const int mk = mask[b * 2048 + q0 + c];
    const float sc = mk ? 0.1803368801f : 0.0f;  // 0.125 * log2(e); 0 => uniform row

    float m = 0.0f;
    f32x4 lacc = (f32x4)0.0f;
    f32x16 oacc0 = (f32x16)0.0f, oacc1 = (f32x16)0.0f;

    // ---- stage tile kt into buffer bufi (4 gload_lds per wave) ----
    auto STAGE = [&](int kt, int bufi) {
        const char* ktile = (const char*)Kb + (size_t)kt * 8192;      // contiguous
        const char* vtile = (const char*)Vb + (size_t)kt * 128;       // strided rows
        char* kdst = (char*)&ldsK[bufi][0] + wave * 2048;
        char* vdst = (char*)&ldsV[bufi][0] + wave * 2048;
#pragma unroll
        for (int i = 0; i < 2; i++) {
            const int row = wave * 16 + i * 8 + srow;
            GLOAD_LDS16(ktile + row * 128 + schunk * 16, kdst + i * 1024);
            GLOAD_LDS16(vtile + (size_t)row * 4096 + schunk * 16, vdst + i * 1024);
        }
    };

    STAGE(0, 0);
    __syncthreads();

    for (int kt = 0; kt < 32; kt++) {
        const int cur = kt & 1;
        if (kt < 31) STAGE(kt + 1, cur ^ 1);
        const char* kbuf = (const char*)&ldsK[cur][0];
        const char* vbuf = (const char*)&ldsV[cur][0];

        // ---- S^T = K Q^T ----
        f32x16 sacc0 = (f32x16)0.0f, sacc1 = (f32x16)0.0f;
        __builtin_amdgcn_s_setprio(1);
#pragma unroll
        for (int ds = 0; ds < 4; ds++) {
            bf16x8 k0 = *reinterpret_cast<const bf16x8*>(kbuf + offL[ds]);
            bf16x8 k1 = *reinterpret_cast<const bf16x8*>(kbuf + offH[ds]);
            sacc0 = MFMA32(k0, qf[ds], sacc0);
            sacc1 = MFMA32(k1, qf[ds], sacc1);
        }
        __builtin_amdgcn_s_setprio(0);

        // ---- raw row max (in-lane tree + one cross-hi shfl) ----
        float t[16];
#pragma unroll
        for (int j = 0; j < 16; j++) t[j] = fmaxf(sacc0[j], sacc1[j]);
#pragma unroll
        for (int s = 8; s >= 1; s >>= 1)
#pragma unroll
            for (int j = 0; j < s; j++) t[j] = fmaxf(t[j], t[j + s]);
        const float rmax = fmaxf(t[0], __shfl_xor(t[0], 32, 64));
        const float pmax2 = rmax * sc;  // base-2 domain

        // ---- defer-max rescale (rare) ----
        if (__any(pmax2 - m > 8.0f)) {
            const float mn = fmaxf(m, pmax2);
            const float alpha = fexp2(m - mn);
            m = mn;
            lacc *= alpha;
#pragma unroll
            for (int reg = 0; reg < 16; reg++) {
                const float ar = __shfl(alpha, (reg & 3) + 8 * (reg >> 2) + 4 * hi, 64);
                oacc0[reg] *= ar;
                oacc1[reg] *= ar;
            }
        }

        // ---- P = 2^(S*sc - m) in place, vector l accumulation ----
#pragma unroll
        for (int j = 0; j < 16; j++) {
            const float p0 = fexp2(fmaf(sacc0[j], sc, -m));
            const float p1 = fexp2(fmaf(sacc1[j], sc, -m));
            sacc0[j] = p0;
            sacc1[j] = p1;
            lacc[j & 3] += p0 + p1;
        }

        // ---- half 0: pack P(keys 0..31) and accumulate PV ----
        {
            uint32_t w0[8];
#pragma unroll
            for (int i = 0; i < 8; i++) w0[i] = pkbf(sacc0[2 * i], sacc0[2 * i + 1]);
            uint32_t s00 = __shfl_xor(hi ? w0[0] : w0[2], 32, 64);
            uint32_t s01 = __shfl_xor(hi ? w0[1] : w0[3], 32, 64);
            uint32_t s02 = __shfl_xor(hi ? w0[4] : w0[6], 32, 64);
            uint32_t s03 = __shfl_xor(hi ? w0[5] : w0[7], 32, 64);
            union { uint32_t u[4]; bf16x8 v; } pa[2];
            if (hi == 0) {
                pa[0].u[0] = w0[0]; pa[0].u[1] = w0[1]; pa[0].u[2] = s00; pa[0].u[3] = s01;
                pa[1].u[0] = w0[4]; pa[1].u[1] = w0[5]; pa[1].u[2] = s02; pa[1].u[3] = s03;
            } else {
                pa[0].u[0] = s00; pa[0].u[1] = s01; pa[0].u[2] = w0[2]; pa[0].u[3] = w0[3];
                pa[1].u[0] = s02; pa[1].u[1] = s03; pa[1].u[2] = w0[6]; pa[1].u[3] = w0[7];
            }
            __builtin_amdgcn_s_setprio(1);
#pragma unroll
            for (int ks = 0; ks < 2; ks++) {
                bf16x8 v0 = *reinterpret_cast<const bf16x8*>(vbuf + offL[ks]);
                bf16x8 v1 = *reinterpret_cast<const bf16x8*>(vbuf + offH[ks]);
                oacc0 = MFMA32(pa[ks].v, v0, oacc0);
                oacc1 = MFMA32(pa[ks].v, v1, oacc1);
            }
            __builtin_amdgcn_s_setprio(0);
        }
        // ---- half 1: pack P(keys 32..63) and accumulate PV ----
        {
            uint32_t w1[8];
#pragma unroll
            for (int i = 0; i < 8; i++) w1[i] = pkbf(sacc1[2 * i], sacc1[2 * i + 1]);
            uint32_t s10 = __shfl_xor(hi ? w1[0] : w1[2], 32, 64);
            uint32_t s11 = __shfl_xor(hi ? w1[1] : w1[3], 32, 64);
            uint32_t s12 = __shfl_xor(hi ? w1[4] : w1[6], 32, 64);
            uint32_t s13 = __shfl_xor(hi ? w1[5] : w1[7], 32, 64);
            union { uint32_t u[4]; bf16x8 v; } pa[2];
            if (hi == 0) {
                pa[0].u[0] = w1[0]; pa[0].u[1] = w1[1]; pa[0].u[2] = s10; pa[0].u[3] = s11;
                pa[1].u[0] = w1[4]; pa[1].u[1] = w1[5]; pa[1].u[2] = s12; pa[1].u[3] = s13;
            } else {
                pa[0].u[0] = s10; pa[0].u[1] = s11; pa[0].u[2] = w1[2]; pa[0].u[3] = w1[3];
                pa[1].u[0] = s12; pa[1].u[1] = s13; pa[1].u[2] = w1[6]; pa[1].u[3] = w1[7];
            }
            __builtin_amdgcn_s_setprio(1);
#pragma unroll
            for (int ks = 0; ks < 2; ks++) {
                bf16x8 v0 = *reinterpret_cast<const bf16x8*>(vbuf + offL[2 + ks]);
                bf16x8 v1 = *reinterpret_cast<const bf16x8*>(vbuf + offH[2 + ks]);
                oacc0 = MFMA32(pa[ks].v, v0, oacc0);
                oacc1 = MFMA32(pa[ks].v, v1, oacc1);
            }
            __builtin_amdgcn_s_setprio(0);
        }

        __syncthreads();  // drains stage (vmcnt) + all LDS reads before swap
    }

    // ---- final l: horizontal sum of lacc + cross-hi ----
    float ls = lacc[0] + lacc[1] + lacc[2] + lacc[3];
    ls += __shfl_xor(ls, 32, 64);
    const float invl = 1.0f / ls;

#pragma unroll
    for (int reg = 0; reg < 16; reg++) {
        const int rr = (reg & 3) + 8 * (reg >> 2) + 4 * hi;
        const float ir = __shfl(invl, rr, 64);
        const size_t rowoff = (size_t)(b * 2048 + q0 + rr) * 1024 + h * 64 + c;
        O[rowoff]      = oacc0[reg] * ir;
        O[rowoff + 32] = oacc1[reg] * ir;
    }
}

// ---------------------------------------------------------------------------
// Residual + LayerNorm: out = LN(O + queries) * gamma + beta, per row of 1024.
// ---------------------------------------------------------------------------
__global__ __launch_bounds__(256) void resid_ln(const float* __restrict__ O,
                                                const float* __restrict__ Qin,
                                                const float* __restrict__ gamma,
                                                const float* __restrict__ beta,
                                                float* __restrict__ out) {
    __shared__ float red[4];
    const int row = blockIdx.x, tid = threadIdx.x;
    const size_t base = (size_t)row * 1024 + tid * 4;
    float4 o4 = *reinterpret_cast<const float4*>(O + base);
    float4 q4 = *reinterpret_cast<const float4*>(Qin + base);
    float x0 = o4.x + q4.x, x1 = o4.y + q4.y, x2 = o4.z + q4.z, x3 = o4.w + q4.w;

    float s = x0 + x1 + x2 + x3;
#pragma unroll
    for (int off = 32; off >= 1; off >>= 1) s += __shfl_xor(s, off, 64);
    const int w = tid >> 6;
    if ((tid & 63) == 0) red[w] = s;
    __syncthreads();
    const float mean = (red[0] + red[1] + red[2] + red[3]) * (1.0f / 1024.0f);
    __syncthreads();

    const float d0 = x0 - mean, d1 = x1 - mean, d2 = x2 - mean, d3 = x3 - mean;
    float vs = d0 * d0 + d1 * d1 + d2 * d2 + d3 * d3;
#pragma unroll
    for (int off = 32; off >= 1; off >>= 1) vs += __shfl_xor(vs, off, 64);
    if ((tid & 63) == 0) red[w] = vs;
    __syncthreads();
    const float var = (red[0] + red[1] + red[2] + red[3]) * (1.0f / 1024.0f);
    const float rstd = rsqrtf(var + 1e-5f);

    float4 g = *reinterpret_cast<const float4*>(gamma + tid * 4);
    float4 be = *reinterpret_cast<const float4*>(beta + tid * 4);
    float4 r;
    r.x = d0 * rstd * g.x + be.x;
    r.y = d1 * rstd * g.y + be.y;
    r.z = d2 * rstd * g.z + be.z;
    r.w = d3 * rstd * g.w + be.w;
    *reinterpret_cast<float4*>(out + base) = r;
}

// ---------------------------------------------------------------------------
extern "C" void kernel_launch(void* const* d_in, const int* in_sizes, int n_in,
                              void* d_out, int out_size, void* d_ws, size_t ws_size,
                              hipStream_t stream) {
    const float* q_in = (const float*)d_in[0];
    const float* k_in = (const float*)d_in[1];
    const float* v_in = (const float*)d_in[2];
    const int* mask = (const int*)d_in[3];
    const float* Wq = (const float*)d_in[4];
    const float* bq = (const float*)d_in[5];
    const float* Wk = (const float*)d_in[6];
    const float* bk = (const float*)d_in[7];
    const float* Wv = (const float*)d_in[8];
    const float* bv = (const float*)d_in[9];
    const float* gamma = (const float*)d_in[10];
    const float* beta = (const float*)d_in[11];
    float* out = (float*)d_out;

    unsigned short* wtq = (unsigned short*)d_ws;         // 1M bf16
    unsigned short* wtk = wtq + 1024 * 1024;
    unsigned short* wtv = wtk + 1024 * 1024;
    unsigned short* Qb = wtv + 1024 * 1024;              // 8M bf16 each
    unsigned short* Kb = Qb + 8192 * 1024;
    unsigned short* Vtb = Kb + 8192 * 1024;
    float* Obuf = (float*)(Vtb + 8192 * 1024);           // 8M fp32

    dim3 tb(256);
    wt_cast<<<dim3(32, 32), tb, 0, stream>>>(Wq, wtq);
    wt_cast<<<dim3(32, 32), tb, 0, stream>>>(Wk, wtk);
    wt_cast<<<dim3(32, 32), tb, 0, stream>>>(Wv, wtv);
    qkv_gemm<0><<<dim3(8, 64), tb, 0, stream>>>(q_in, wtq, bq, Qb);
    qkv_gemm<0><<<dim3(8, 64), tb, 0, stream>>>(k_in, wtk, bk, Kb);
    qkv_gemm<1><<<dim3(8, 64), tb, 0, stream>>>(v_in, wtv, bv, Vtb);
    flash_attn<<<dim3(1024), tb, 0, stream>>>(Qb, Kb, Vtb, mask, Obuf);
    resid_ln<<<dim3(8192), tb, 0, stream>>>(Obuf, q_in, gamma, beta, out);
}

// Round 6
// 241.912 us; speedup vs baseline: 1.5947x; 1.0859x over previous
//
#include <hip/hip_runtime.h>
#include <hip/hip_bf16.h>
#include <stdint.h>

typedef __bf16 bf16x8 __attribute__((ext_vector_type(8)));
typedef float f32x4 __attribute__((ext_vector_type(4)));
typedef float f32x16 __attribute__((ext_vector_type(16)));
typedef unsigned short ushort8v __attribute__((ext_vector_type(8)));
typedef unsigned short ushort4v __attribute__((ext_vector_type(4)));
typedef uint32_t uint2v __attribute__((ext_vector_type(2)));

#define MFMA16(a, b, c) __builtin_amdgcn_mfma_f32_16x16x32_bf16(a, b, c, 0, 0, 0)
#define MFMA32(a, b, c) __builtin_amdgcn_mfma_f32_32x32x16_bf16(a, b, c, 0, 0, 0)

// async global->LDS, 16B per lane; LDS dest = wave-uniform base + lane*16
#define GLOAD_LDS16(g, l)                                                        \
    __builtin_amdgcn_global_load_lds(                                            \
        (const __attribute__((address_space(1))) uint32_t*)(g),                  \
        (__attribute__((address_space(3))) uint32_t*)(l), 16, 0, 0)

__device__ __forceinline__ unsigned short f2bf_u(float f) {
    union { float f; uint32_t u; } cv; cv.f = f;
    uint32_t u = cv.u;
    uint32_t r = (u + 0x7FFFu + ((u >> 16) & 1u)) >> 16;
    return (unsigned short)r;
}

__device__ __forceinline__ uint32_t pkbf(float a, float b) {
    union { __hip_bfloat162 h; uint32_t u; } cv;
    cv.h = __float22bfloat162_rn(make_float2(a, b));
    return cv.u;
}

__device__ __forceinline__ float fexp2(float x) { return __builtin_amdgcn_exp2f(x); }

// ---------------------------------------------------------------------------
// Transpose + cast: Wt[n][k] = bf16(W[k][n]); z selects Wq/Wk/Wv.
// ---------------------------------------------------------------------------
__global__ __launch_bounds__(256) void wt_cast(const float* __restrict__ W0,
                                               const float* __restrict__ W1,
                                               const float* __restrict__ W2,
                                               unsigned short* __restrict__ T0,
                                               unsigned short* __restrict__ T1,
                                               unsigned short* __restrict__ T2) {
    const int z = blockIdx.z;
    const float* W = z == 0 ? W0 : (z == 1 ? W1 : W2);
    unsigned short* Wt = z == 0 ? T0 : (z == 1 ? T1 : T2);
    __shared__ float t[32][33];
    const int tx = threadIdx.x & 31, ty = threadIdx.x >> 5;  // 32 x 8
    const int n0 = blockIdx.x * 32, k0 = blockIdx.y * 32;
#pragma unroll
    for (int i = 0; i < 4; i++) {
        int r = i * 8 + ty;
        t[r][tx] = W[(size_t)(k0 + r) * 1024 + n0 + tx];
    }
    __syncthreads();
#pragma unroll
    for (int i = 0; i < 4; i++) {
        int r = i * 8 + ty;
        Wt[(size_t)(n0 + r) * 1024 + k0 + tx] = f2bf_u(t[tx][r]);
    }
}

// ---------------------------------------------------------------------------
// QKV GEMM v2 (m97 pattern): out = relu(A[8192x1024] @ W + bias).
// A fp32 (reg-staged, issue-early/write-late), Wt bf16 [N][K] via
// global_load_lds; BK=32 double-buffered, one barrier per K-step.
// blockIdx.z selects {Q,K,V}; z==2 writes V transposed [B,H,dh,S].
// ---------------------------------------------------------------------------
__global__ __launch_bounds__(256) void qkv_gemm2(
    const float* __restrict__ Aq, const float* __restrict__ Ak, const float* __restrict__ Av,
    const unsigned short* __restrict__ Wq, const unsigned short* __restrict__ Wk,
    const unsigned short* __restrict__ Wv,
    const float* __restrict__ biasq, const float* __restrict__ biask,
    const float* __restrict__ biasv,
    unsigned short* __restrict__ outq, unsigned short* __restrict__ outk,
    unsigned short* __restrict__ outv) {
    __shared__ __align__(16) unsigned short aS[2][128 * 32];
    __shared__ __align__(16) unsigned short wS[2][128 * 32];
    const int z = blockIdx.z;
    const float* A = z == 0 ? Aq : (z == 1 ? Ak : Av);
    const unsigned short* Wt = z == 0 ? Wq : (z == 1 ? Wk : Wv);
    const float* bias = z == 0 ? biasq : (z == 1 ? biask : biasv);
    unsigned short* out = z == 0 ? outq : (z == 1 ? outk : outv);
    const bool vt = (z == 2);

    const int tid = threadIdx.x;
    const int lane = tid & 63, wave = tid >> 6;
    const int rrow = lane & 15, rgrp = lane >> 4;
    const int m0 = blockIdx.y * 128, n0 = blockIdx.x * 128;
    const int wm = wave >> 1, wn = wave & 1;

    // W staging: thread covers chunks g = tid, tid+256 of [128 rows x 4 chunks]
    const int wrow0 = tid >> 2, wc0 = tid & 3;          // g  = tid
    const int wrow1 = (tid + 256) >> 2;                  // g2 = tid+256 (wc same)
    // A staging: 4 coalesced chunk-loads g = i*256+tid; row=g>>3, qc=g&7
    // fragment rows
    const int arow_f = wm * 64 + rrow;                   // + mi*16
    const int brow_f = wn * 64 + rrow;                   // + ni*16

    f32x4 acc[4][4];
#pragma unroll
    for (int i = 0; i < 4; i++)
#pragma unroll
        for (int j = 0; j < 4; j++) acc[i][j] = (f32x4)0.0f;

    auto STAGE_W = [&](int k0, int bufi) {
        const char* src = (const char*)Wt;
        char* dst = (char*)&wS[bufi][0] + wave * 1024;   // + implicit lane*16
        GLOAD_LDS16(src + ((size_t)(n0 + wrow0) * 1024 + k0 + wc0 * 8) * 2, dst);
        GLOAD_LDS16(src + ((size_t)(n0 + wrow1) * 1024 + k0 + wc0 * 8) * 2, dst + 4096);
    };
    auto LOAD_A = [&](int k0, float4* r) {
#pragma unroll
        for (int i = 0; i < 4; i++) {
            const int g = i * 256 + tid, row = g >> 3, qc = g & 7;
            r[i] = *reinterpret_cast<const float4*>(A + (size_t)(m0 + row) * 1024 + k0 + qc * 4);
        }
    };
    auto WRITE_A = [&](const float4* r, int bufi) {
#pragma unroll
        for (int i = 0; i < 4; i++) {
            const int g = i * 256 + tid, row = g >> 3, qc = g & 7;
            uint2v w;
            w[0] = pkbf(r[i].x, r[i].y);
            w[1] = pkbf(r[i].z, r[i].w);
            *reinterpret_cast<uint2v*>((char*)&aS[bufi][0] + row * 64 + qc * 8) = w;
        }
    };

    {
        float4 a0[4];
        STAGE_W(0, 0);
        LOAD_A(0, a0);
        WRITE_A(a0, 0);
    }
    __syncthreads();

    for (int ks = 0; ks < 32; ks++) {
        const int cur = ks & 1;
        float4 anx[4];
        if (ks < 31) {
            STAGE_W((ks + 1) * 32, cur ^ 1);
            LOAD_A((ks + 1) * 32, anx);
        }

        bf16x8 af[4], bfr[4];
#pragma unroll
        for (int mi = 0; mi < 4; mi++)
            af[mi] = *reinterpret_cast<const bf16x8*>(
                (const char*)&aS[cur][0] + (arow_f + mi * 16) * 64 + rgrp * 16);
#pragma unroll
        for (int ni = 0; ni < 4; ni++)
            bfr[ni] = *reinterpret_cast<const bf16x8*>(
                (const char*)&wS[cur][0] + (brow_f + ni * 16) * 64 + rgrp * 16);
        __builtin_amdgcn_s_setprio(1);
#pragma unroll
        for (int mi = 0; mi < 4; mi++)
#pragma unroll
            for (int ni = 0; ni < 4; ni++)
                acc[mi][ni] = MFMA16(af[mi], bfr[ni], acc[mi][ni]);
        __builtin_amdgcn_s_setprio(0);

        if (ks < 31) WRITE_A(anx, cur ^ 1);
        __syncthreads();
    }

    // Epilogue: bias + relu + bf16, scatter into head-split layout.
#pragma unroll
    for (int mi = 0; mi < 4; mi++) {
#pragma unroll
        for (int ni = 0; ni < 4; ni++) {
            const int n = n0 + wn * 64 + ni * 16 + rrow;
            const float bv = bias[n];
            const int h = n >> 6, d = n & 63;
            const int mbase = m0 + wm * 64 + mi * 16 + rgrp * 4;
            const int b = mbase >> 11, s = mbase & 2047;
            if (vt) {
                ushort4v pv;
#pragma unroll
                for (int jr = 0; jr < 4; jr++)
                    pv[jr] = f2bf_u(fmaxf(acc[mi][ni][jr] + bv, 0.0f));
                *reinterpret_cast<ushort4v*>(out + ((size_t)((b * 16 + h) * 64 + d)) * 2048 + s) = pv;
            } else {
#pragma unroll
                for (int jr = 0; jr < 4; jr++)
                    out[((size_t)((b * 16 + h) * 2048 + (s + jr))) * 64 + d] =
                        f2bf_u(fmaxf(acc[mi][ni][jr] + bv, 0.0f));
            }
        }
    }
}

// ---------------------------------------------------------------------------
// Flash attention. 4 waves/block share one (b,h); K/V tiles staged to LDS via
// global_load_lds (double-buffered 2-phase). Swapped-QK^T 32x32. Since Q,K are
// ReLU'd, scores are >= 0 and bounded (S*log2e/8 <= ~47 << 127), so softmax
// uses a FIXED m=0: no row max, no rescale, P >= 1 so l >= tile count.
// l is accumulated by MFMA (P . ones) into the same row layout as O.
// ---------------------------------------------------------------------------
__global__ __launch_bounds__(256, 4) void flash_attn(const unsigned short* __restrict__ Qg,
                                                     const unsigned short* __restrict__ Kg,
                                                     const unsigned short* __restrict__ Vt,
                                                     const int* __restrict__ mask,
                                                     float* __restrict__ O) {
    __shared__ __align__(16) unsigned short ldsK[2][64 * 64];  // 8KB per buffer
    __shared__ __align__(16) unsigned short ldsV[2][64 * 64];
    const int tid = threadIdx.x;
    const int lane = tid & 63, wave = tid >> 6;
    const int c = lane & 31, hi = lane >> 5;
    const int bid = blockIdx.x;                      // 1024 blocks
    const int swzb = (bid & 7) * 128 + (bid >> 3);   // XCD-contiguous block id
    const int gid = swzb * 4 + wave;                 // wave id in [0,4096)
    const int bh = gid >> 6;                         // all 4 waves: same bh
    const int q0 = (gid & 63) * 32;
    const int b = bh >> 4, h = bh & 15;
    const size_t base = (size_t)bh * (2048 * 64);
    const unsigned short* Qb = Qg + base;
    const unsigned short* Kb = Kg + base;
    const unsigned short* Vb = Vt + base;  // [64][2048]

    // staging constants: lane covers 16B chunk (lane&7) of row stripe (lane>>3)
    const int srow = lane >> 3;                 // 0..7
    const int schunk = (lane & 7) ^ srow;       // inverse-swizzled source chunk
    int offL[4], offH[4];
#pragma unroll
    for (int ds = 0; ds < 4; ds++) {
        offL[ds] = c * 128 + ((((ds << 1) + hi) ^ (c & 7)) << 4);
        offH[ds] = offL[ds] + 32 * 128;
    }

    bf16x8 qf[4];
#pragma unroll
    for (int ds = 0; ds < 4; ds++)
        qf[ds] = *reinterpret_cast<const bf16x8*>(Qb + (size_t)(q0 + c) * 64 + ds * 16 + hi * 8);

    const int mk = mask[b * 2048 + q0 + c];
    const float sc = mk ? 0.1803368801f : 0.0f;  // 0.125 * log2(e); 0 => uniform row

    union { uint32_t u[4]; bf16x8 v; } onesf;
#pragma unroll
    for (int i = 0; i < 4; i++) onesf.u[i] = 0x3F803F80u;  // bf16 1.0 x8

    f32x16 lacc = (f32x16)0.0f;
    f32x16 oacc0 = (f32x16)0.0f, oacc1 = (f32x16)0.0f;

    auto STAGE = [&](int kt, int bufi) {
        const char* ktile = (const char*)Kb + (size_t)kt * 8192;      // contiguous
        const char* vtile = (const char*)Vb + (size_t)kt * 128;       // strided rows
        char* kdst = (char*)&ldsK[bufi][0] + wave * 2048;
        char* vdst = (char*)&ldsV[bufi][0] + wave * 2048;
#pragma unroll
        for (int i = 0; i < 2; i++) {
            const int row = wave * 16 + i * 8 + srow;
            GLOAD_LDS16(ktile + row * 128 + schunk * 16, kdst + i * 1024);
            GLOAD_LDS16(vtile + (size_t)row * 4096 + schunk * 16, vdst + i * 1024);
        }
    };

    STAGE(0, 0);
    __syncthreads();

    for (int kt = 0; kt < 32; kt++) {
        const int cur = kt & 1;
        if (kt < 31) STAGE(kt + 1, cur ^ 1);
        const char* kbuf = (const char*)&ldsK[cur][0];
        const char* vbuf = (const char*)&ldsV[cur][0];

        // ---- S^T = K Q^T ----
        f32x16 sacc0 = (f32x16)0.0f, sacc1 = (f32x16)0.0f;
        __builtin_amdgcn_s_setprio(1);
#pragma unroll
        for (int ds = 0; ds < 4; ds++) {
            bf16x8 k0 = *reinterpret_cast<const bf16x8*>(kbuf + offL[ds]);
            bf16x8 k1 = *reinterpret_cast<const bf16x8*>(kbuf + offH[ds]);
            sacc0 = MFMA32(k0, qf[ds], sacc0);
            sacc1 = MFMA32(k1, qf[ds], sacc1);
        }
        __builtin_amdgcn_s_setprio(0);

        // ---- P = 2^(S*sc) in place (fixed m=0; safe since S bounded) ----
#pragma unroll
        for (int j = 0; j < 16; j++) {
            sacc0[j] = fexp2(sacc0[j] * sc);
            sacc1[j] = fexp2(sacc1[j] * sc);
        }

        // ---- half 0: pack P(keys 0..31), l += P.1, O += P V ----
        {
            uint32_t w0[8];
#pragma unroll
            for (int i = 0; i < 8; i++) w0[i] = pkbf(sacc0[2 * i], sacc0[2 * i + 1]);
            uint32_t s00 = __shfl_xor(hi ? w0[0] : w0[2], 32, 64);
            uint32_t s01 = __shfl_xor(hi ? w0[1] : w0[3], 32, 64);
            uint32_t s02 = __shfl_xor(hi ? w0[4] : w0[6], 32, 64);
            uint32_t s03 = __shfl_xor(hi ? w0[5] : w0[7], 32, 64);
            union { uint32_t u[4]; bf16x8 v; } pa[2];
            if (hi == 0) {
                pa[0].u[0] = w0[0]; pa[0].u[1] = w0[1]; pa[0].u[2] = s00; pa[0].u[3] = s01;
                pa[1].u[0] = w0[4]; pa[1].u[1] = w0[5]; pa[1].u[2] = s02; pa[1].u[3] = s03;
            } else {
                pa[0].u[0] = s00; pa[0].u[1] = s01; pa[0].u[2] = w0[2]; pa[0].u[3] = w0[3];
                pa[1].u[0] = s02; pa[1].u[1] = s03; pa[1].u[2] = w0[6]; pa[1].u[3] = w0[7];
            }
            __builtin_amdgcn_s_setprio(1);
#pragma unroll
            for (int ks = 0; ks < 2; ks++) {
                bf16x8 v0 = *reinterpret_cast<const bf16x8*>(vbuf + offL[ks]);
                bf16x8 v1 = *reinterpret_cast<const bf16x8*>(vbuf + offH[ks]);
                lacc = MFMA32(pa[ks].v, onesf.v, lacc);
                oacc0 = MFMA32(pa[ks].v, v0, oacc0);
                oacc1 = MFMA32(pa[ks].v, v1, oacc1);
            }
            __builtin_amdgcn_s_setprio(0);
        }
        // ---- half 1: keys 32..63 ----
        {
            uint32_t w1[8];
#pragma unroll
            for (int i = 0; i < 8; i++) w1[i] = pkbf(sacc1[2 * i], sacc1[2 * i + 1]);
            uint32_t s10 = __shfl_xor(hi ? w1[0] : w1[2], 32, 64);
            uint32_t s11 = __shfl_xor(hi ? w1[1] : w1[3], 32, 64);
            uint32_t s12 = __shfl_xor(hi ? w1[4] : w1[6], 32, 64);
            uint32_t s13 = __shfl_xor(hi ? w1[5] : w1[7], 32, 64);
            union { uint32_t u[4]; bf16x8 v; } pa[2];
            if (hi == 0) {
                pa[0].u[0] = w1[0]; pa[0].u[1] = w1[1]; pa[0].u[2] = s10; pa[0].u[3] = s11;
                pa[1].u[0] = w1[4]; pa[1].u[1] = w1[5]; pa[1].u[2] = s12; pa[1].u[3] = s13;
            } else {
                pa[0].u[0] = s10; pa[0].u[1] = s11; pa[0].u[2] = w1[2]; pa[0].u[3] = w1[3];
                pa[1].u[0] = s12; pa[1].u[1] = s13; pa[1].u[2] = w1[6]; pa[1].u[3] = w1[7];
            }
            __builtin_amdgcn_s_setprio(1);
#pragma unroll
            for (int ks = 0; ks < 2; ks++) {
                bf16x8 v0 = *reinterpret_cast<const bf16x8*>(vbuf + offL[2 + ks]);
                bf16x8 v1 = *reinterpret_cast<const bf16x8*>(vbuf + offH[2 + ks]);
                lacc = MFMA32(pa[ks].v, onesf.v, lacc);
                oacc0 = MFMA32(pa[ks].v, v0, oacc0);
                oacc1 = MFMA32(pa[ks].v, v1, oacc1);
            }
            __builtin_amdgcn_s_setprio(0);
        }

        __syncthreads();  // drains stage (vmcnt) + all LDS reads before swap
    }

    // ---- normalize + write O: lacc rows match oacc rows exactly ----
#pragma unroll
    for (int reg = 0; reg < 16; reg++) {
        const int rr = (reg & 3) + 8 * (reg >> 2) + 4 * hi;
        const float ir = 1.0f / lacc[reg];
        const size_t rowoff = (size_t)(b * 2048 + q0 + rr) * 1024 + h * 64 + c;
        O[rowoff]      = oacc0[reg] * ir;
        O[rowoff + 32] = oacc1[reg] * ir;
    }
}

// ---------------------------------------------------------------------------
// Residual + LayerNorm: out = LN(O + queries) * gamma + beta, per row of 1024.
// ---------------------------------------------------------------------------
__global__ __launch_bounds__(256) void resid_ln(const float* __restrict__ O,
                                                const float* __restrict__ Qin,
                                                const float* __restrict__ gamma,
                                                const float* __restrict__ beta,
                                                float* __restrict__ out) {
    __shared__ float red[4];
    const int row = blockIdx.x, tid = threadIdx.x;
    const size_t base = (size_t)row * 1024 + tid * 4;
    float4 o4 = *reinterpret_cast<const float4*>(O + base);
    float4 q4 = *reinterpret_cast<const float4*>(Qin + base);
    float x0 = o4.x + q4.x, x1 = o4.y + q4.y, x2 = o4.z + q4.z, x3 = o4.w + q4.w;

    float s = x0 + x1 + x2 + x3;
#pragma unroll
    for (int off = 32; off >= 1; off >>= 1) s += __shfl_xor(s, off, 64);
    const int w = tid >> 6;
    if ((tid & 63) == 0) red[w] = s;
    __syncthreads();
    const float mean = (red[0] + red[1] + red[2] + red[3]) * (1.0f / 1024.0f);
    __syncthreads();

    const float d0 = x0 - mean, d1 = x1 - mean, d2 = x2 - mean, d3 = x3 - mean;
    float vs = d0 * d0 + d1 * d1 + d2 * d2 + d3 * d3;
#pragma unroll
    for (int off = 32; off >= 1; off >>= 1) vs += __shfl_xor(vs, off, 64);
    if ((tid & 63) == 0) red[w] = vs;
    __syncthreads();
    const float var = (red[0] + red[1] + red[2] + red[3]) * (1.0f / 1024.0f);
    const float rstd = rsqrtf(var + 1e-5f);

    float4 g = *reinterpret_cast<const float4*>(gamma + tid * 4);
    float4 be = *reinterpret_cast<const float4*>(beta + tid * 4);
    float4 r;
    r.x = d0 * rstd * g.x + be.x;
    r.y = d1 * rstd * g.y + be.y;
    r.z = d2 * rstd * g.z + be.z;
    r.w = d3 * rstd * g.w + be.w;
    *reinterpret_cast<float4*>(out + base) = r;
}

// ---------------------------------------------------------------------------
extern "C" void kernel_launch(void* const* d_in, const int* in_sizes, int n_in,
                              void* d_out, int out_size, void* d_ws, size_t ws_size,
                              hipStream_t stream) {
    const float* q_in = (const float*)d_in[0];
    const float* k_in = (const float*)d_in[1];
    const float* v_in = (const float*)d_in[2];
    const int* mask = (const int*)d_in[3];
    const float* Wq = (const float*)d_in[4];
    const float* bq = (const float*)d_in[5];
    const float* Wk = (const float*)d_in[6];
    const float* bk = (const float*)d_in[7];
    const float* Wv = (const float*)d_in[8];
    const float* bv = (const float*)d_in[9];
    const float* gamma = (const float*)d_in[10];
    const float* beta = (const float*)d_in[11];
    float* out = (float*)d_out;

    unsigned short* wtq = (unsigned short*)d_ws;         // 1M bf16
    unsigned short* wtk = wtq + 1024 * 1024;
    unsigned short* wtv = wtk + 1024 * 1024;
    unsigned short* Qb = wtv + 1024 * 1024;              // 8M bf16 each
    unsigned short* Kb = Qb + 8192 * 1024;
    unsigned short* Vtb = Kb + 8192 * 1024;
    float* Obuf = (float*)(Vtb + 8192 * 1024);           // 8M fp32

    dim3 tb(256);
    wt_cast<<<dim3(32, 32, 3), tb, 0, stream>>>(Wq, Wk, Wv, wtq, wtk, wtv);
    qkv_gemm2<<<dim3(8, 64, 3), tb, 0, stream>>>(q_in, k_in, v_in, wtq, wtk, wtv,
                                                 bq, bk, bv, Qb, Kb, Vtb);
    flash_attn<<<dim3(1024), tb, 0, stream>>>(Qb, Kb, Vtb, mask, Obuf);
    resid_ln<<<dim3(8192), tb, 0, stream>>>(Obuf, q_in, gamma, beta, out);
}

// Round 7
// 205.413 us; speedup vs baseline: 1.8781x; 1.1777x over previous
//
#include <hip/hip_runtime.h>
#include <hip/hip_bf16.h>
#include <stdint.h>

typedef __bf16 bf16x8 __attribute__((ext_vector_type(8)));
typedef float f32x4 __attribute__((ext_vector_type(4)));
typedef float f32x16 __attribute__((ext_vector_type(16)));
typedef unsigned short ushort8v __attribute__((ext_vector_type(8)));
typedef unsigned short ushort4v __attribute__((ext_vector_type(4)));
typedef uint32_t uint2v __attribute__((ext_vector_type(2)));

#define MFMA16(a, b, c) __builtin_amdgcn_mfma_f32_16x16x32_bf16(a, b, c, 0, 0, 0)
#define MFMA32(a, b, c) __builtin_amdgcn_mfma_f32_32x32x16_bf16(a, b, c, 0, 0, 0)

// async global->LDS, 16B per lane; LDS dest = wave-uniform base + lane*16
#define GLOAD_LDS16(g, l)                                                        \
    __builtin_amdgcn_global_load_lds(                                            \
        (const __attribute__((address_space(1))) uint32_t*)(g),                  \
        (__attribute__((address_space(3))) uint32_t*)(l), 16, 0, 0)

__device__ __forceinline__ unsigned short f2bf_u(float f) {
    union { float f; uint32_t u; } cv; cv.f = f;
    uint32_t u = cv.u;
    uint32_t r = (u + 0x7FFFu + ((u >> 16) & 1u)) >> 16;
    return (unsigned short)r;
}

__device__ __forceinline__ uint32_t pkbf(float a, float b) {
    union { __hip_bfloat162 h; uint32_t u; } cv;
    cv.h = __float22bfloat162_rn(make_float2(a, b));
    return cv.u;
}

__device__ __forceinline__ float fexp2(float x) { return __builtin_amdgcn_exp2f(x); }

// ---------------------------------------------------------------------------
// Transpose + cast: Wt[n][k] = bf16(W[k][n]); z selects Wq/Wk/Wv.
// ---------------------------------------------------------------------------
__global__ __launch_bounds__(256) void wt_cast(const float* __restrict__ W0,
                                               const float* __restrict__ W1,
                                               const float* __restrict__ W2,
                                               unsigned short* __restrict__ T0,
                                               unsigned short* __restrict__ T1,
                                               unsigned short* __restrict__ T2) {
    const int z = blockIdx.z;
    const float* W = z == 0 ? W0 : (z == 1 ? W1 : W2);
    unsigned short* Wt = z == 0 ? T0 : (z == 1 ? T1 : T2);
    __shared__ float t[32][33];
    const int tx = threadIdx.x & 31, ty = threadIdx.x >> 5;  // 32 x 8
    const int n0 = blockIdx.x * 32, k0 = blockIdx.y * 32;
#pragma unroll
    for (int i = 0; i < 4; i++) {
        int r = i * 8 + ty;
        t[r][tx] = W[(size_t)(k0 + r) * 1024 + n0 + tx];
    }
    __syncthreads();
#pragma unroll
    for (int i = 0; i < 4; i++) {
        int r = i * 8 + ty;
        Wt[(size_t)(n0 + r) * 1024 + k0 + tx] = f2bf_u(t[tx][r]);
    }
}

// ---------------------------------------------------------------------------
// QKV GEMM v2 (m97 pattern): out = relu(A[8192x1024] @ W + bias).
// A fp32 (reg-staged, issue-early/write-late), Wt bf16 [N][K] via
// global_load_lds; BK=32 double-buffered, one barrier per K-step.
// 1-D grid 1536, in-kernel XCD-aware remap: XCD x owns m-panels [8x,8x+8)
// (4MB of A = its L2), n fastest so 8 consecutive blocks share one A-panel.
// ---------------------------------------------------------------------------
__global__ __launch_bounds__(256) void qkv_gemm2(
    const float* __restrict__ Aq, const float* __restrict__ Ak, const float* __restrict__ Av,
    const unsigned short* __restrict__ Wq, const unsigned short* __restrict__ Wk,
    const unsigned short* __restrict__ Wv,
    const float* __restrict__ biasq, const float* __restrict__ biask,
    const float* __restrict__ biasv,
    unsigned short* __restrict__ outq, unsigned short* __restrict__ outk,
    unsigned short* __restrict__ outv) {
    __shared__ __align__(16) unsigned short aS[2][128 * 32];
    __shared__ __align__(16) unsigned short wS[2][128 * 32];
    const int id = blockIdx.x;          // 0..1535
    const int xcd = id & 7;
    const int local = id >> 3;          // 0..191
    const int z = local >> 6;           // 0..2
    const int l2i = local & 63;         // 0..63
    const int m0 = (xcd * 8 + (l2i >> 3)) * 128;
    const int n0 = (l2i & 7) * 128;

    const float* A = z == 0 ? Aq : (z == 1 ? Ak : Av);
    const unsigned short* Wt = z == 0 ? Wq : (z == 1 ? Wk : Wv);
    const float* bias = z == 0 ? biasq : (z == 1 ? biask : biasv);
    unsigned short* out = z == 0 ? outq : (z == 1 ? outk : outv);
    const bool vt = (z == 2);

    const int tid = threadIdx.x;
    const int lane = tid & 63, wave = tid >> 6;
    const int rrow = lane & 15, rgrp = lane >> 4;
    const int wm = wave >> 1, wn = wave & 1;

    // W staging: thread covers chunks g = tid, tid+256 of [128 rows x 4 chunks]
    const int wrow0 = tid >> 2, wc0 = tid & 3;          // g  = tid
    const int wrow1 = (tid + 256) >> 2;                  // g2 = tid+256 (wc same)
    const int arow_f = wm * 64 + rrow;                   // + mi*16
    const int brow_f = wn * 64 + rrow;                   // + ni*16

    f32x4 acc[4][4];
#pragma unroll
    for (int i = 0; i < 4; i++)
#pragma unroll
        for (int j = 0; j < 4; j++) acc[i][j] = (f32x4)0.0f;

    auto STAGE_W = [&](int k0, int bufi) {
        const char* src = (const char*)Wt;
        char* dst = (char*)&wS[bufi][0] + wave * 1024;   // + implicit lane*16
        GLOAD_LDS16(src + ((size_t)(n0 + wrow0) * 1024 + k0 + wc0 * 8) * 2, dst);
        GLOAD_LDS16(src + ((size_t)(n0 + wrow1) * 1024 + k0 + wc0 * 8) * 2, dst + 4096);
    };
    auto LOAD_A = [&](int k0, float4* r) {
#pragma unroll
        for (int i = 0; i < 4; i++) {
            const int g = i * 256 + tid, row = g >> 3, qc = g & 7;
            r[i] = *reinterpret_cast<const float4*>(A + (size_t)(m0 + row) * 1024 + k0 + qc * 4);
        }
    };
    auto WRITE_A = [&](const float4* r, int bufi) {
#pragma unroll
        for (int i = 0; i < 4; i++) {
            const int g = i * 256 + tid, row = g >> 3, qc = g & 7;
            uint2v w;
            w[0] = pkbf(r[i].x, r[i].y);
            w[1] = pkbf(r[i].z, r[i].w);
            *reinterpret_cast<uint2v*>((char*)&aS[bufi][0] + row * 64 + qc * 8) = w;
        }
    };

    {
        float4 a0[4];
        STAGE_W(0, 0);
        LOAD_A(0, a0);
        WRITE_A(a0, 0);
    }
    __syncthreads();

    for (int ks = 0; ks < 32; ks++) {
        const int cur = ks & 1;
        float4 anx[4];
        if (ks < 31) {
            STAGE_W((ks + 1) * 32, cur ^ 1);
            LOAD_A((ks + 1) * 32, anx);
        }

        bf16x8 af[4], bfr[4];
#pragma unroll
        for (int mi = 0; mi < 4; mi++)
            af[mi] = *reinterpret_cast<const bf16x8*>(
                (const char*)&aS[cur][0] + (arow_f + mi * 16) * 64 + rgrp * 16);
#pragma unroll
        for (int ni = 0; ni < 4; ni++)
            bfr[ni] = *reinterpret_cast<const bf16x8*>(
                (const char*)&wS[cur][0] + (brow_f + ni * 16) * 64 + rgrp * 16);
        __builtin_amdgcn_s_setprio(1);
#pragma unroll
        for (int mi = 0; mi < 4; mi++)
#pragma unroll
            for (int ni = 0; ni < 4; ni++)
                acc[mi][ni] = MFMA16(af[mi], bfr[ni], acc[mi][ni]);
        __builtin_amdgcn_s_setprio(0);

        if (ks < 31) WRITE_A(anx, cur ^ 1);
        __syncthreads();
    }

    // Epilogue: bias + relu + bf16, scatter into head-split layout.
#pragma unroll
    for (int mi = 0; mi < 4; mi++) {
#pragma unroll
        for (int ni = 0; ni < 4; ni++) {
            const int n = n0 + wn * 64 + ni * 16 + rrow;
            const float bv = bias[n];
            const int h = n >> 6, d = n & 63;
            const int mbase = m0 + wm * 64 + mi * 16 + rgrp * 4;
            const int b = mbase >> 11, s = mbase & 2047;
            if (vt) {
                ushort4v pv;
#pragma unroll
                for (int jr = 0; jr < 4; jr++)
                    pv[jr] = f2bf_u(fmaxf(acc[mi][ni][jr] + bv, 0.0f));
                *reinterpret_cast<ushort4v*>(out + ((size_t)((b * 16 + h) * 64 + d)) * 2048 + s) = pv;
            } else {
#pragma unroll
                for (int jr = 0; jr < 4; jr++)
                    out[((size_t)((b * 16 + h) * 2048 + (s + jr))) * 64 + d] =
                        f2bf_u(fmaxf(acc[mi][ni][jr] + bv, 0.0f));
            }
        }
    }
}

// ---------------------------------------------------------------------------
// Flash attention. 4 waves/block share one (b,h); K/V tiles staged to LDS via
// global_load_lds (double-buffered 2-phase). Swapped-QK^T 32x32. Since Q,K are
// ReLU'd, scores are >= 0 and bounded (S*log2e/8 <= ~47 << 127), so softmax
// uses a FIXED m=0: no row max, no rescale, P >= 1 so l >= tile count.
// l is accumulated by MFMA (P . ones) into the same row layout as O.
// ---------------------------------------------------------------------------
__global__ __launch_bounds__(256, 4) void flash_attn(const unsigned short* __restrict__ Qg,
                                                     const unsigned short* __restrict__ Kg,
                                                     const unsigned short* __restrict__ Vt,
                                                     const int* __restrict__ mask,
                                                     float* __restrict__ O) {
    __shared__ __align__(16) unsigned short ldsK[2][64 * 64];  // 8KB per buffer
    __shared__ __align__(16) unsigned short ldsV[2][64 * 64];
    const int tid = threadIdx.x;
    const int lane = tid & 63, wave = tid >> 6;
    const int c = lane & 31, hi = lane >> 5;
    const int bid = blockIdx.x;                      // 1024 blocks
    const int swzb = (bid & 7) * 128 + (bid >> 3);   // XCD-contiguous block id
    const int gid = swzb * 4 + wave;                 // wave id in [0,4096)
    const int bh = gid >> 6;                         // all 4 waves: same bh
    const int q0 = (gid & 63) * 32;
    const int b = bh >> 4, h = bh & 15;
    const size_t base = (size_t)bh * (2048 * 64);
    const unsigned short* Qb = Qg + base;
    const unsigned short* Kb = Kg + base;
    const unsigned short* Vb = Vt + base;  // [64][2048]

    // staging constants: lane covers 16B chunk (lane&7) of row stripe (lane>>3)
    const int srow = lane >> 3;                 // 0..7
    const int schunk = (lane & 7) ^ srow;       // inverse-swizzled source chunk
    int offL[4], offH[4];
#pragma unroll
    for (int ds = 0; ds < 4; ds++) {
        offL[ds] = c * 128 + ((((ds << 1) + hi) ^ (c & 7)) << 4);
        offH[ds] = offL[ds] + 32 * 128;
    }

    bf16x8 qf[4];
#pragma unroll
    for (int ds = 0; ds < 4; ds++)
        qf[ds] = *reinterpret_cast<const bf16x8*>(Qb + (size_t)(q0 + c) * 64 + ds * 16 + hi * 8);

    const int mk = mask[b * 2048 + q0 + c];
    const float sc = mk ? 0.1803368801f : 0.0f;  // 0.125 * log2(e); 0 => uniform row

    union { uint32_t u[4]; bf16x8 v; } onesf;
#pragma unroll
    for (int i = 0; i < 4; i++) onesf.u[i] = 0x3F803F80u;  // bf16 1.0 x8

    f32x16 lacc = (f32x16)0.0f;
    f32x16 oacc0 = (f32x16)0.0f, oacc1 = (f32x16)0.0f;

    auto STAGE = [&](int kt, int bufi) {
        const char* ktile = (const char*)Kb + (size_t)kt * 8192;      // contiguous
        const char* vtile = (const char*)Vb + (size_t)kt * 128;       // strided rows
        char* kdst = (char*)&ldsK[bufi][0] + wave * 2048;
        char* vdst = (char*)&ldsV[bufi][0] + wave * 2048;
#pragma unroll
        for (int i = 0; i < 2; i++) {
            const int row = wave * 16 + i * 8 + srow;
            GLOAD_LDS16(ktile + row * 128 + schunk * 16, kdst + i * 1024);
            GLOAD_LDS16(vtile + (size_t)row * 4096 + schunk * 16, vdst + i * 1024);
        }
    };

    STAGE(0, 0);
    __syncthreads();

    for (int kt = 0; kt < 32; kt++) {
        const int cur = kt & 1;
        if (kt < 31) STAGE(kt + 1, cur ^ 1);
        const char* kbuf = (const char*)&ldsK[cur][0];
        const char* vbuf = (const char*)&ldsV[cur][0];

        // ---- S^T = K Q^T ----
        f32x16 sacc0 = (f32x16)0.0f, sacc1 = (f32x16)0.0f;
        __builtin_amdgcn_s_setprio(1);
#pragma unroll
        for (int ds = 0; ds < 4; ds++) {
            bf16x8 k0 = *reinterpret_cast<const bf16x8*>(kbuf + offL[ds]);
            bf16x8 k1 = *reinterpret_cast<const bf16x8*>(kbuf + offH[ds]);
            sacc0 = MFMA32(k0, qf[ds], sacc0);
            sacc1 = MFMA32(k1, qf[ds], sacc1);
        }
        __builtin_amdgcn_s_setprio(0);

        // ---- P = 2^(S*sc) in place (fixed m=0; safe since S bounded) ----
#pragma unroll
        for (int j = 0; j < 16; j++) {
            sacc0[j] = fexp2(sacc0[j] * sc);
            sacc1[j] = fexp2(sacc1[j] * sc);
        }

        // ---- half 0: pack P(keys 0..31), l += P.1, O += P V ----
        {
            uint32_t w0[8];
#pragma unroll
            for (int i = 0; i < 8; i++) w0[i] = pkbf(sacc0[2 * i], sacc0[2 * i + 1]);
            uint32_t s00 = __shfl_xor(hi ? w0[0] : w0[2], 32, 64);
            uint32_t s01 = __shfl_xor(hi ? w0[1] : w0[3], 32, 64);
            uint32_t s02 = __shfl_xor(hi ? w0[4] : w0[6], 32, 64);
            uint32_t s03 = __shfl_xor(hi ? w0[5] : w0[7], 32, 64);
            union { uint32_t u[4]; bf16x8 v; } pa[2];
            if (hi == 0) {
                pa[0].u[0] = w0[0]; pa[0].u[1] = w0[1]; pa[0].u[2] = s00; pa[0].u[3] = s01;
                pa[1].u[0] = w0[4]; pa[1].u[1] = w0[5]; pa[1].u[2] = s02; pa[1].u[3] = s03;
            } else {
                pa[0].u[0] = s00; pa[0].u[1] = s01; pa[0].u[2] = w0[2]; pa[0].u[3] = w0[3];
                pa[1].u[0] = s02; pa[1].u[1] = s03; pa[1].u[2] = w0[6]; pa[1].u[3] = w0[7];
            }
            __builtin_amdgcn_s_setprio(1);
#pragma unroll
            for (int ks = 0; ks < 2; ks++) {
                bf16x8 v0 = *reinterpret_cast<const bf16x8*>(vbuf + offL[ks]);
                bf16x8 v1 = *reinterpret_cast<const bf16x8*>(vbuf + offH[ks]);
                lacc = MFMA32(pa[ks].v, onesf.v, lacc);
                oacc0 = MFMA32(pa[ks].v, v0, oacc0);
                oacc1 = MFMA32(pa[ks].v, v1, oacc1);
            }
            __builtin_amdgcn_s_setprio(0);
        }
        // ---- half 1: keys 32..63 ----
        {
            uint32_t w1[8];
#pragma unroll
            for (int i = 0; i < 8; i++) w1[i] = pkbf(sacc1[2 * i], sacc1[2 * i + 1]);
            uint32_t s10 = __shfl_xor(hi ? w1[0] : w1[2], 32, 64);
            uint32_t s11 = __shfl_xor(hi ? w1[1] : w1[3], 32, 64);
            uint32_t s12 = __shfl_xor(hi ? w1[4] : w1[6], 32, 64);
            uint32_t s13 = __shfl_xor(hi ? w1[5] : w1[7], 32, 64);
            union { uint32_t u[4]; bf16x8 v; } pa[2];
            if (hi == 0) {
                pa[0].u[0] = w1[0]; pa[0].u[1] = w1[1]; pa[0].u[2] = s10; pa[0].u[3] = s11;
                pa[1].u[0] = w1[4]; pa[1].u[1] = w1[5]; pa[1].u[2] = s12; pa[1].u[3] = s13;
            } else {
                pa[0].u[0] = s10; pa[0].u[1] = s11; pa[0].u[2] = w1[2]; pa[0].u[3] = w1[3];
                pa[1].u[0] = s12; pa[1].u[1] = s13; pa[1].u[2] = w1[6]; pa[1].u[3] = w1[7];
            }
            __builtin_amdgcn_s_setprio(1);
#pragma unroll
            for (int ks = 0; ks < 2; ks++) {
                bf16x8 v0 = *reinterpret_cast<const bf16x8*>(vbuf + offL[2 + ks]);
                bf16x8 v1 = *reinterpret_cast<const bf16x8*>(vbuf + offH[2 + ks]);
                lacc = MFMA32(pa[ks].v, onesf.v, lacc);
                oacc0 = MFMA32(pa[ks].v, v0, oacc0);
                oacc1 = MFMA32(pa[ks].v, v1, oacc1);
            }
            __builtin_amdgcn_s_setprio(0);
        }

        __syncthreads();  // drains stage (vmcnt) + all LDS reads before swap
    }

    // ---- normalize + write O: lacc rows match oacc rows exactly ----
#pragma unroll
    for (int reg = 0; reg < 16; reg++) {
        const int rr = (reg & 3) + 8 * (reg >> 2) + 4 * hi;
        const float ir = 1.0f / lacc[reg];
        const size_t rowoff = (size_t)(b * 2048 + q0 + rr) * 1024 + h * 64 + c;
        O[rowoff]      = oacc0[reg] * ir;
        O[rowoff + 32] = oacc1[reg] * ir;
    }
}

// ---------------------------------------------------------------------------
// Residual + LayerNorm: out = LN(O + queries) * gamma + beta, per row of 1024.
// ---------------------------------------------------------------------------
__global__ __launch_bounds__(256) void resid_ln(const float* __restrict__ O,
                                                const float* __restrict__ Qin,
                                                const float* __restrict__ gamma,
                                                const float* __restrict__ beta,
                                                float* __restrict__ out) {
    __shared__ float red[4];
    const int row = blockIdx.x, tid = threadIdx.x;
    const size_t base = (size_t)row * 1024 + tid * 4;
    float4 o4 = *reinterpret_cast<const float4*>(O + base);
    float4 q4 = *reinterpret_cast<const float4*>(Qin + base);
    float x0 = o4.x + q4.x, x1 = o4.y + q4.y, x2 = o4.z + q4.z, x3 = o4.w + q4.w;

    float s = x0 + x1 + x2 + x3;
#pragma unroll
    for (int off = 32; off >= 1; off >>= 1) s += __shfl_xor(s, off, 64);
    const int w = tid >> 6;
    if ((tid & 63) == 0) red[w] = s;
    __syncthreads();
    const float mean = (red[0] + red[1] + red[2] + red[3]) * (1.0f / 1024.0f);
    __syncthreads();

    const float d0 = x0 - mean, d1 = x1 - mean, d2 = x2 - mean, d3 = x3 - mean;
    float vs = d0 * d0 + d1 * d1 + d2 * d2 + d3 * d3;
#pragma unroll
    for (int off = 32; off >= 1; off >>= 1) vs += __shfl_xor(vs, off, 64);
    if ((tid & 63) == 0) red[w] = vs;
    __syncthreads();
    const float var = (red[0] + red[1] + red[2] + red[3]) * (1.0f / 1024.0f);
    const float rstd = rsqrtf(var + 1e-5f);

    float4 g = *reinterpret_cast<const float4*>(gamma + tid * 4);
    float4 be = *reinterpret_cast<const float4*>(beta + tid * 4);
    float4 r;
    r.x = d0 * rstd * g.x + be.x;
    r.y = d1 * rstd * g.y + be.y;
    r.z = d2 * rstd * g.z + be.z;
    r.w = d3 * rstd * g.w + be.w;
    *reinterpret_cast<float4*>(out + base) = r;
}

// ---------------------------------------------------------------------------
extern "C" void kernel_launch(void* const* d_in, const int* in_sizes, int n_in,
                              void* d_out, int out_size, void* d_ws, size_t ws_size,
                              hipStream_t stream) {
    const float* q_in = (const float*)d_in[0];
    const float* k_in = (const float*)d_in[1];
    const float* v_in = (const float*)d_in[2];
    const int* mask = (const int*)d_in[3];
    const float* Wq = (const float*)d_in[4];
    const float* bq = (const float*)d_in[5];
    const float* Wk = (const float*)d_in[6];
    const float* bk = (const float*)d_in[7];
    const float* Wv = (const float*)d_in[8];
    const float* bv = (const float*)d_in[9];
    const float* gamma = (const float*)d_in[10];
    const float* beta = (const float*)d_in[11];
    float* out = (float*)d_out;

    unsigned short* wtq = (unsigned short*)d_ws;         // 1M bf16
    unsigned short* wtk = wtq + 1024 * 1024;
    unsigned short* wtv = wtk + 1024 * 1024;
    unsigned short* Qb = wtv + 1024 * 1024;              // 8M bf16 each
    unsigned short* Kb = Qb + 8192 * 1024;
    unsigned short* Vtb = Kb + 8192 * 1024;
    float* Obuf = (float*)(Vtb + 8192 * 1024);           // 8M fp32

    dim3 tb(256);
    wt_cast<<<dim3(32, 32, 3), tb, 0, stream>>>(Wq, Wk, Wv, wtq, wtk, wtv);
    qkv_gemm2<<<dim3(1536), tb, 0, stream>>>(q_in, k_in, v_in, wtq, wtk, wtv,
                                             bq, bk, bv, Qb, Kb, Vtb);
    flash_attn<<<dim3(1024), tb, 0, stream>>>(Qb, Kb, Vtb, mask, Obuf);
    resid_ln<<<dim3(8192), tb, 0, stream>>>(Obuf, q_in, gamma, beta, out);
}